// Round 13
// baseline (1236.074 us; speedup 1.0000x reference)
//
#include <hip/hip_runtime.h>
#include <hip/hip_bf16.h>
#include <cstdint>
#include <cstddef>

// Problem constants
#define T_TOK   2048   // 4 sequences (2 question + 2 answer) x 512
#define DM      768
#define DI      1536
#define NST     16
#define RRANK   48
#define KCONV   4
#define VOCAB   50280
#define NLAYER  4
#define SEQL    512
#define NTILE_V 197    // ceil(50280/256)
#define NCHUNK  8      // time chunks per sequence
#define CHL     64     // chunk length
#define NCAT    1568   // 32 (B,C) + 1536 (dt) fused projection cols

typedef __bf16 bf16x8 __attribute__((ext_vector_type(8)));
typedef float  f32x4  __attribute__((ext_vector_type(4)));

__device__ inline unsigned short f2b(float f) {
  union { float f; unsigned u; } v; v.f = f;
  unsigned r = v.u + 0x7FFFu + ((v.u >> 16) & 1u);   // RNE
  return (unsigned short)(r >> 16);
}
__device__ inline float b2f(unsigned short h) {
  union { unsigned u; float f; } v; v.u = ((unsigned)h) << 16;
  return v.f;
}

// global -> LDS direct 16B async copy. LDS dest is wave-uniform base; HW
// scatters lane i to base + i*16.
__device__ inline void gload_lds16(const unsigned short* g, unsigned short* l) {
  __builtin_amdgcn_global_load_lds(
      (const __attribute__((address_space(1))) void*)g,
      (__attribute__((address_space(3))) void*)l, 16, 0, 0);
}

// ---------------------------------------------------------------------------
// Transpose-convert: src f32 [R][C] -> dst bf16 [C][Rpad] (zero pad r>=R).
__global__ __launch_bounds__(256) void transpose_conv_kernel(
    const float* __restrict__ src, unsigned short* __restrict__ dst,
    int R, int C, int Rpad) {
  __shared__ float tile[32][33];
  const float* s = src + (size_t)blockIdx.z * R * C;
  unsigned short* d = dst + (size_t)blockIdx.z * C * Rpad;
  int c0 = blockIdx.x * 32, r0 = blockIdx.y * 32;
  int tx = threadIdx.x & 31, ty = threadIdx.x >> 5; // ty 0..7
  #pragma unroll
  for (int i = 0; i < 32; i += 8) {
    int r = r0 + ty + i, c = c0 + tx;
    tile[ty + i][tx] = (r < R && c < C) ? s[(size_t)r * C + c] : 0.f;
  }
  __syncthreads();
  #pragma unroll
  for (int i = 0; i < 32; i += 8) {
    int c = c0 + ty + i, r = r0 + tx;
    if (c < C && r < Rpad) d[(size_t)c * Rpad + r] = f2b(tile[tx][ty + i]);
  }
}

// ---------------------------------------------------------------------------
// embed f32 -> bf16 (grid-stride)
__global__ __launch_bounds__(256) void cvt_embed_kernel(
    const float* __restrict__ e, unsigned short* __restrict__ eb) {
  const int n4 = VOCAB * DM / 4;
  for (int i = blockIdx.x * 256 + threadIdx.x; i < n4; i += gridDim.x * 256) {
    float4 f = *(const float4*)(e + (size_t)i * 4);
    union { unsigned long long u; unsigned short h[4]; } pk;
    pk.h[0] = f2b(f.x); pk.h[1] = f2b(f.y); pk.h[2] = f2b(f.z); pk.h[3] = f2b(f.w);
    *(unsigned long long*)(eb + (size_t)i * 4) = pk.u;
  }
}

// ---------------------------------------------------------------------------
// W_cat rows 0..31: copy xpw cols 48..79 transposed.  Grid (192, NL).
__global__ __launch_bounds__(256) void wcat_bc_kernel(
    const float* __restrict__ xpw, unsigned short* __restrict__ wcat) {
  int l = blockIdx.y;
  int idx = blockIdx.x * 256 + threadIdx.x;   // 32*1536
  int n = idx / DI, k = idx - n * DI;
  wcat[(size_t)l * NCAT * DI + (size_t)n * DI + k] =
      f2b(xpw[(size_t)l * DI * 80 + (size_t)k * 80 + 48 + n]);
}

// ---------------------------------------------------------------------------
// W_cat rows 32..1567: Wdt[k][d] = sum_r xpw[k][r]*dtw[r][d], stored [32+d][k].
// Grid (24 ktiles, 24 dtiles, NL), 64x64 tile per block.
__global__ __launch_bounds__(256) void wdt_kernel(
    const float* __restrict__ xpw, const float* __restrict__ dtw,
    unsigned short* __restrict__ wcat) {
  __shared__ float xs[64][49];
  __shared__ float ds[48][64];
  int l = blockIdx.z;
  int k0 = blockIdx.x * 64, n0 = blockIdx.y * 64;
  const float* xp = xpw + (size_t)l * DI * 80;
  const float* dp = dtw + (size_t)l * RRANK * DI;
  int tid = threadIdx.x;
  {
    int row = tid >> 2, cg = (tid & 3) * 12;
    #pragma unroll
    for (int c = 0; c < 12; ++c)
      xs[row][cg + c] = xp[(size_t)(k0 + row) * 80 + cg + c];
    int col = tid & 63, rb = tid >> 6;
    #pragma unroll
    for (int i = 0; i < 12; ++i)
      ds[rb + 4 * i][col] = dp[(size_t)(rb + 4 * i) * DI + n0 + col];
  }
  __syncthreads();
  int tx = tid & 63, ty = tid >> 6;
  float acc[16] = {};
  #pragma unroll 8
  for (int r = 0; r < 48; ++r) {
    float xv = xs[tx][r];
    #pragma unroll
    for (int i = 0; i < 16; ++i) acc[i] += xv * ds[r][ty + 4 * i];
  }
  unsigned short* wl = wcat + (size_t)l * NCAT * DI + (size_t)(32 + n0) * DI;
  #pragma unroll
  for (int i = 0; i < 16; ++i)
    wl[(size_t)(ty + 4 * i) * DI + k0 + tx] = f2b(acc[i]);
}

// ---------------------------------------------------------------------------
// Fused embedding gather + layer-0 RMSNorm.  Grid T_TOK blocks.
__global__ __launch_bounds__(256) void gather_rms_kernel(
    const int* __restrict__ qids, const int* __restrict__ qmask,
    const int* __restrict__ aids, const int* __restrict__ amask,
    const float* __restrict__ embed, const float* __restrict__ w,
    float* __restrict__ x, unsigned short* __restrict__ h) {
  int t = blockIdx.x;
  int seq = t >> 9, pos = t & 511;
  const int* ids = (seq < 2) ? qids : aids;
  const int* msk = (seq < 2) ? qmask : amask;
  int s2 = seq & 1;
  int id = ids[s2 * SEQL + pos];
  float m = (float)msk[s2 * SEQL + pos];
  const float* er = embed + (size_t)id * DM;
  float v[3], ss = 0.f;
  #pragma unroll
  for (int j = 0; j < 3; ++j) {
    int d = threadIdx.x + j * 256;
    float vv = er[d] * m;
    x[(size_t)t * DM + d] = vv;
    v[j] = vv; ss += vv * vv;
  }
  for (int o = 1; o < 64; o <<= 1) ss += __shfl_xor(ss, o);
  __shared__ float wsum[4];
  if ((threadIdx.x & 63) == 0) wsum[threadIdx.x >> 6] = ss;
  __syncthreads();
  ss = wsum[0] + wsum[1] + wsum[2] + wsum[3];
  float sc = rsqrtf(ss / (float)DM + 1e-5f);
  #pragma unroll
  for (int j = 0; j < 3; ++j) {
    int d = threadIdx.x + j * 256;
    h[(size_t)t * DM + d] = f2b(v[j] * sc * w[d]);
  }
}

// ---------------------------------------------------------------------------
// Fused: x += sum(out_proj partials); h = rms(x)*w  (next layer / final norm)
__global__ __launch_bounds__(256) void resid_rms_kernel(
    float* __restrict__ x, const float* __restrict__ part,
    const float* __restrict__ w, unsigned short* __restrict__ h) {
  int t = blockIdx.x;
  float v[3];
  float ss = 0.f;
  #pragma unroll
  for (int j = 0; j < 3; ++j) {
    int d = threadIdx.x + j * 256;
    size_t o = (size_t)t * DM + d;
    float xv = x[o] + part[o] + part[(size_t)T_TOK * DM + o] +
               part[(size_t)2 * T_TOK * DM + o] + part[(size_t)3 * T_TOK * DM + o];
    x[o] = xv; v[j] = xv; ss += xv * xv;
  }
  for (int o = 1; o < 64; o <<= 1) ss += __shfl_xor(ss, o);
  __shared__ float wsum[4];
  if ((threadIdx.x & 63) == 0) wsum[threadIdx.x >> 6] = ss;
  __syncthreads();
  ss = wsum[0] + wsum[1] + wsum[2] + wsum[3];
  float sc = rsqrtf(ss / (float)DM + 1e-5f);
  #pragma unroll
  for (int j = 0; j < 3; ++j) {
    int d = threadIdx.x + j * 256;
    h[(size_t)t * DM + d] = f2b(v[j] * sc * w[d]);
  }
}

// ---------------------------------------------------------------------------
// Narrow GEMM (128x128, 4 waves), single-buffered + XOR-swizzle.
// EPI 6 only: split-K partial C[(split*M+row)*ldc+col].
template <int EPI>
__global__ __launch_bounds__(256) void gemm_bf16_kernel(
    const unsigned short* __restrict__ A, int lda,
    const unsigned short* __restrict__ B, int ldb,
    float* __restrict__ C, int ldc,
    int M, int N, int K, int mtiles) {
  __shared__ __attribute__((aligned(16))) unsigned short As[128 * 64];
  __shared__ __attribute__((aligned(16))) unsigned short Bs[128 * 64];
  int bid = blockIdx.x;
  int m0 = (bid % mtiles) * 128;
  int rest = bid / mtiles;
  int ntil = (N + 127) >> 7;
  int split = rest / ntil;
  int n0 = (rest % ntil) * 128;
  const unsigned short* Ap = A + (size_t)split * K;
  const unsigned short* Bp = B + (size_t)split * K;
  int tid = threadIdx.x;
  int lane = tid & 63, w = tid >> 6;
  int wr = w >> 1, wc = w & 1;
  f32x4 acc[4][4] = {};

  int lrow = lane >> 3;
  int lcol = (((lane & 7) ^ (lrow & 7)) & 7) * 8;
  auto STAGE = [&](int k0) {
    #pragma unroll
    for (int it = 0; it < 4; ++it) {
      int r = w * 32 + it * 8;
      gload_lds16(Ap + (size_t)(m0 + r + lrow) * lda + k0 + lcol, &As[r * 64]);
      int br = n0 + r + lrow; if (br > N - 1) br = N - 1;
      gload_lds16(Bp + (size_t)br * ldb + k0 + lcol, &Bs[r * 64]);
    }
  };

  int nst = K / 64;
  int rA = wr * 64 + (lane & 15);
  int rB = wc * 64 + (lane & 15);
  int sw = lane & 7, ckb = lane >> 4;
  for (int s = 0; s < nst; ++s) {
    STAGE(s * 64);
    __syncthreads();
    __builtin_amdgcn_s_setprio(1);
    #pragma unroll
    for (int ks = 0; ks < 2; ++ks) {
      int ca = (((ks * 4 + ckb) ^ sw) & 7) * 8;
      bf16x8 a[4], b[4];
      #pragma unroll
      for (int i = 0; i < 4; ++i) a[i] = *(const bf16x8*)(&As[(rA + i * 16) * 64 + ca]);
      #pragma unroll
      for (int i = 0; i < 4; ++i) b[i] = *(const bf16x8*)(&Bs[(rB + i * 16) * 64 + ca]);
      #pragma unroll
      for (int mi = 0; mi < 4; ++mi)
        #pragma unroll
        for (int ni = 0; ni < 4; ++ni)
          acc[mi][ni] = __builtin_amdgcn_mfma_f32_16x16x32_bf16(a[mi], b[ni], acc[mi][ni], 0, 0, 0);
    }
    __builtin_amdgcn_s_setprio(0);
    __syncthreads();
  }

  int g = lane >> 4, c = lane & 15;
  #pragma unroll
  for (int mi = 0; mi < 4; ++mi)
    #pragma unroll
    for (int ni = 0; ni < 4; ++ni) {
      int col = n0 + wc * 64 + ni * 16 + c;
      int row0 = m0 + wr * 64 + mi * 16 + g * 4;
      if (col < N) {
        #pragma unroll
        for (int r = 0; r < 4; ++r)
          C[((size_t)split * M + row0 + r) * ldc + col] = acc[mi][ni][r];
      }
    }
}

// ---------------------------------------------------------------------------
// Wide GEMM: 128x256 tile, 8 waves (2Mx4N), BK=64, single-buffered 48KB LDS.
// EPI 7 = in_proj: col<DI -> O1[row*DI+col]=u raw; col>=DI -> silu ->
//         OT[(col-DI)*T_TOK+row] transposed float4
// EPI 8 = fused BC/dt: col<32 -> O1(BCt)[col*T_TOK+row] float4;
//         32<=col<NCAT -> softplus(acc+bias[col-32]) -> OT(dtT) float4
template <int EPI>
__global__ __launch_bounds__(512) void gemm_wide_kernel(
    const unsigned short* __restrict__ A, int lda,
    const unsigned short* __restrict__ B, int ldb,
    float* __restrict__ O1, float* __restrict__ OT,
    const float* __restrict__ bias,
    int N, int K, int mtiles) {
  __shared__ __attribute__((aligned(16))) unsigned short As[128 * 64];
  __shared__ __attribute__((aligned(16))) unsigned short Bs[256 * 64];
  int bid = blockIdx.x;
  int m0 = (bid % mtiles) * 128;
  int n0 = (bid / mtiles) * 256;
  int tid = threadIdx.x;
  int lane = tid & 63, w = tid >> 6;   // 8 waves
  int wr = w >> 2, wc = w & 3;         // 2 x 4; per-wave output 64x64
  f32x4 acc[4][4] = {};

  int lrow = lane >> 3;
  int lcol = (((lane & 7) ^ (lrow & 7)) & 7) * 8;
  auto STAGE = [&](int k0) {
    #pragma unroll
    for (int it = 0; it < 2; ++it) {            // A: 8 waves x 16 rows
      int r = w * 16 + it * 8;
      gload_lds16(A + (size_t)(m0 + r + lrow) * lda + k0 + lcol, &As[r * 64]);
    }
    #pragma unroll
    for (int it = 0; it < 4; ++it) {            // B: 8 waves x 32 rows
      int r = w * 32 + it * 8;
      int br = n0 + r + lrow; if (br > N - 1) br = N - 1;
      gload_lds16(B + (size_t)br * ldb + k0 + lcol, &Bs[r * 64]);
    }
  };

  int nst = K / 64;
  int rA = wr * 64 + (lane & 15);
  int rB = wc * 64 + (lane & 15);
  int sw = lane & 7, ckb = lane >> 4;
  for (int s = 0; s < nst; ++s) {
    STAGE(s * 64);
    __syncthreads();
    __builtin_amdgcn_s_setprio(1);
    #pragma unroll
    for (int ks = 0; ks < 2; ++ks) {
      int ca = (((ks * 4 + ckb) ^ sw) & 7) * 8;
      bf16x8 a[4], b[4];
      #pragma unroll
      for (int i = 0; i < 4; ++i) a[i] = *(const bf16x8*)(&As[(rA + i * 16) * 64 + ca]);
      #pragma unroll
      for (int i = 0; i < 4; ++i) b[i] = *(const bf16x8*)(&Bs[(rB + i * 16) * 64 + ca]);
      #pragma unroll
      for (int mi = 0; mi < 4; ++mi)
        #pragma unroll
        for (int ni = 0; ni < 4; ++ni)
          acc[mi][ni] = __builtin_amdgcn_mfma_f32_16x16x32_bf16(a[mi], b[ni], acc[mi][ni], 0, 0, 0);
    }
    __builtin_amdgcn_s_setprio(0);
    __syncthreads();
  }

  int g = lane >> 4, c = lane & 15;
  #pragma unroll
  for (int mi = 0; mi < 4; ++mi)
    #pragma unroll
    for (int ni = 0; ni < 4; ++ni) {
      int col = n0 + wc * 64 + ni * 16 + c;
      int row0 = m0 + wr * 64 + mi * 16 + g * 4;
      if (EPI == 7) {
        if (col < DI) {
          #pragma unroll
          for (int r = 0; r < 4; ++r)
            O1[(size_t)(row0 + r) * DI + col] = acc[mi][ni][r];
        } else {
          float4 o; float* ov = (float*)&o;
          #pragma unroll
          for (int r = 0; r < 4; ++r) {
            float zv = acc[mi][ni][r];
            ov[r] = zv / (1.f + __expf(-zv));
          }
          *(float4*)(&OT[(size_t)(col - DI) * T_TOK + row0]) = o;
        }
      }
      if (EPI == 8) {
        if (col < 32) {
          float4 o; float* ov = (float*)&o;
          #pragma unroll
          for (int r = 0; r < 4; ++r) ov[r] = acc[mi][ni][r];
          *(float4*)(&O1[(size_t)col * T_TOK + row0]) = o;
        } else if (col < NCAT) {
          float4 o; float* ov = (float*)&o;
          #pragma unroll
          for (int r = 0; r < 4; ++r) {
            float xv = acc[mi][ni][r] + bias[col - 32];
            ov[r] = (xv > 20.f) ? xv : log1pf(__expf(xv));
          }
          *(float4*)(&OT[(size_t)(col - 32) * T_TOK + row0]) = o;
        }
      }
    }
}

// ---------------------------------------------------------------------------
// Logits GEMM + fused LSE partials.  128x256 tile, 8 waves (unchanged R11).
__global__ __launch_bounds__(512) void gemm_lse_kernel(
    const unsigned short* __restrict__ A,
    const unsigned short* __restrict__ B,
    float* __restrict__ pmax, float* __restrict__ psum,
    int mtiles) {
  __shared__ __attribute__((aligned(16))) unsigned short As[128 * 64];
  __shared__ __attribute__((aligned(16))) unsigned short Bs[256 * 64];
  __shared__ float lmax[128][4];
  __shared__ float lsum[128][4];
  const int K = DM, Nv = VOCAB;
  int bid = blockIdx.x;
  int m0 = (bid % mtiles) * 128;
  int n0 = (bid / mtiles) * 256;
  int tid = threadIdx.x;
  int lane = tid & 63, w = tid >> 6;
  int wr = w >> 2, wc = w & 3;
  f32x4 acc[4][4] = {};

  int lrow = lane >> 3;
  int lcol = (((lane & 7) ^ (lrow & 7)) & 7) * 8;
  auto STAGE = [&](int k0) {
    #pragma unroll
    for (int it = 0; it < 2; ++it) {
      int r = w * 16 + it * 8;
      gload_lds16(A + (size_t)(m0 + r + lrow) * K + k0 + lcol, &As[r * 64]);
    }
    #pragma unroll
    for (int it = 0; it < 4; ++it) {
      int r = w * 32 + it * 8;
      int br = n0 + r + lrow; if (br > Nv - 1) br = Nv - 1;
      gload_lds16(B + (size_t)br * K + k0 + lcol, &Bs[r * 64]);
    }
  };

  const int nst = K / 64;   // 12
  int rA = wr * 64 + (lane & 15);
  int rB = wc * 64 + (lane & 15);
  int sw = lane & 7, ckb = lane >> 4;
  for (int s = 0; s < nst; ++s) {
    STAGE(s * 64);
    __syncthreads();
    __builtin_amdgcn_s_setprio(1);
    #pragma unroll
    for (int ks = 0; ks < 2; ++ks) {
      int ca = (((ks * 4 + ckb) ^ sw) & 7) * 8;
      bf16x8 a[4], b[4];
      #pragma unroll
      for (int i = 0; i < 4; ++i) a[i] = *(const bf16x8*)(&As[(rA + i * 16) * 64 + ca]);
      #pragma unroll
      for (int i = 0; i < 4; ++i) b[i] = *(const bf16x8*)(&Bs[(rB + i * 16) * 64 + ca]);
      #pragma unroll
      for (int mi = 0; mi < 4; ++mi)
        #pragma unroll
        for (int ni = 0; ni < 4; ++ni)
          acc[mi][ni] = __builtin_amdgcn_mfma_f32_16x16x32_bf16(a[mi], b[ni], acc[mi][ni], 0, 0, 0);
    }
    __builtin_amdgcn_s_setprio(0);
    __syncthreads();
  }

  int g = lane >> 4, c = lane & 15;
  #pragma unroll
  for (int mi = 0; mi < 4; ++mi) {
    #pragma unroll
    for (int r = 0; r < 4; ++r) {
      float mx = -INFINITY;
      #pragma unroll
      for (int ni = 0; ni < 4; ++ni) {
        int col = n0 + wc * 64 + ni * 16 + c;
        float v = (col < Nv) ? acc[mi][ni][r] : -INFINITY;
        mx = fmaxf(mx, v);
      }
      mx = fmaxf(mx, __shfl_xor(mx, 1, 16));
      mx = fmaxf(mx, __shfl_xor(mx, 2, 16));
      mx = fmaxf(mx, __shfl_xor(mx, 4, 16));
      mx = fmaxf(mx, __shfl_xor(mx, 8, 16));
      float ssum = 0.f;
      #pragma unroll
      for (int ni = 0; ni < 4; ++ni) {
        int col = n0 + wc * 64 + ni * 16 + c;
        if (col < Nv) ssum += __expf(acc[mi][ni][r] - mx);
      }
      ssum += __shfl_xor(ssum, 1, 16);
      ssum += __shfl_xor(ssum, 2, 16);
      ssum += __shfl_xor(ssum, 4, 16);
      ssum += __shfl_xor(ssum, 8, 16);
      if (c == 0) {
        int rl = wr * 64 + mi * 16 + g * 4 + r;
        lmax[rl][wc] = mx;
        lsum[rl][wc] = ssum;
      }
    }
  }
  __syncthreads();
  if (tid < 128) {
    float m0v = lmax[tid][0], m1 = lmax[tid][1], m2 = lmax[tid][2], m3 = lmax[tid][3];
    float Mx = fmaxf(fmaxf(m0v, m1), fmaxf(m2, m3));
    float S = lsum[tid][0] * __expf(m0v - Mx) + lsum[tid][1] * __expf(m1 - Mx) +
              lsum[tid][2] * __expf(m2 - Mx) + lsum[tid][3] * __expf(m3 - Mx);
    int row = m0 + tid;
    int nb = n0 >> 8;
    pmax[(size_t)row * NTILE_V + nb] = Mx;
    psum[(size_t)row * NTILE_V + nb] = S;
  }
}

// ---------------------------------------------------------------------------
// Tiled causal depthwise conv (K=4) + silu on u only.
__global__ __launch_bounds__(256) void conv_silu_kernel(
    const float* __restrict__ ur, const float* __restrict__ cw,
    const float* __restrict__ cb,
    unsigned short* __restrict__ ucbf, float* __restrict__ ucT) {
  __shared__ float xu[67][64];
  __shared__ float ou[64][65];
  int t0 = blockIdx.x * 64;
  int ch0 = blockIdx.y * 64;
  int tid = threadIdx.x;
  int cx = tid & 63, ty = tid >> 6;           // ty 0..3
  bool seq_start = (t0 & 511) == 0;
  for (int r = ty; r < 67; r += 4) {
    int tg = t0 - 3 + r;
    float v = 0.f;
    if (r >= 3 || !seq_start) v = ur[(size_t)tg * DI + ch0 + cx];
    xu[r][cx] = v;
  }
  __syncthreads();
  int ch = ch0 + cx;
  float4 wv = *(const float4*)(cw + ch * 4);
  float bias = cb[ch];
  #pragma unroll
  for (int i = 0; i < 16; ++i) {
    int tr = ty * 16 + i;
    float a = bias + xu[tr][cx] * wv.x + xu[tr + 1][cx] * wv.y +
              xu[tr + 2][cx] * wv.z + xu[tr + 3][cx] * wv.w;
    float s = a / (1.f + __expf(-a));
    ucbf[(size_t)(t0 + tr) * DI + ch] = f2b(s);
    ou[tr][cx] = s;
  }
  __syncthreads();
  int tx = tid & 63, cy = tid >> 6;
  #pragma unroll
  for (int i = 0; i < 16; ++i) {
    int chi = cy * 16 + i;
    ucT[(size_t)(ch0 + chi) * T_TOK + t0 + tx] = ou[tx][chi];
  }
}

// ---------------------------------------------------------------------------
// Scan phase 1: per-(b,d,n,chunk) summary.
__global__ __launch_bounds__(256) void scan_sum_kernel(
    const float* __restrict__ dtT, const float* __restrict__ ucT,
    const float* __restrict__ BCt, const float* __restrict__ Alog,
    float* __restrict__ Pbuf, float* __restrict__ Fbuf) {
  int bc = blockIdx.x / 96;                 // b*8+chunk
  int idx = (blockIdx.x % 96) * 256 + threadIdx.x;
  int n = idx & 15, d = idx >> 4;
  int b = bc >> 3, chunk = bc & 7;
  float A = -__expf(Alog[d * NST + n]);
  int t0 = b * SEQL + chunk * CHL;
  const float4* dp = (const float4*)(dtT + (size_t)d * T_TOK + t0);
  const float4* up = (const float4*)(ucT + (size_t)d * T_TOK + t0);
  const float4* Bp = (const float4*)(BCt + (size_t)n * T_TOK + t0);
  float h = 0.f, sdt = 0.f;
  #pragma unroll
  for (int q = 0; q < CHL / 4; ++q) {
    float4 d4 = dp[q], u4 = up[q], B4 = Bp[q];
    float a;
    a = __expf(d4.x * A); h = fmaf(a, h, d4.x * u4.x * B4.x);
    a = __expf(d4.y * A); h = fmaf(a, h, d4.y * u4.y * B4.y);
    a = __expf(d4.z * A); h = fmaf(a, h, d4.z * u4.z * B4.z);
    a = __expf(d4.w * A); h = fmaf(a, h, d4.w * u4.w * B4.w);
    sdt += d4.x + d4.y + d4.z + d4.w;
  }
  size_t s = ((size_t)bc * DI + d) * NST + n;
  Pbuf[s] = __expf(A * sdt);
  Fbuf[s] = h;
}

// ---------------------------------------------------------------------------
// Scan phase 3 + fused gate.
__global__ __launch_bounds__(256) void scan_emit_kernel(
    const float* __restrict__ dtT, const float* __restrict__ ucT,
    const float* __restrict__ BCt, const float* __restrict__ zsT,
    const float* __restrict__ Alog, const float* __restrict__ Dpar,
    const float* __restrict__ Pbuf, const float* __restrict__ Fbuf,
    unsigned short* __restrict__ yg) {
  int bc = blockIdx.x / 96;                 // b*8+chunk
  int idx = (blockIdx.x % 96) * 256 + threadIdx.x;
  int n = idx & 15, d = idx >> 4;
  int b = bc >> 3, chunk = bc & 7;
  float A = -__expf(Alog[d * NST + n]);
  float Dpv = Dpar[d];
  float h = 0.f;
  for (int j = 0; j < chunk; ++j) {
    size_t s = (((size_t)(b * NCHUNK + j)) * DI + d) * NST + n;
    h = Fbuf[s] + Pbuf[s] * h;
  }
  int t0 = b * SEQL + chunk * CHL;
  const float4* dp = (const float4*)(dtT + (size_t)d * T_TOK + t0);
  const float4* up = (const float4*)(ucT + (size_t)d * T_TOK + t0);
  const float4* Bp = (const float4*)(BCt + (size_t)n * T_TOK + t0);
  const float4* Cp = (const float4*)(BCt + (size_t)(NST + n) * T_TOK + t0);
  const float4* zp = (const float4*)(zsT + (size_t)d * T_TOK + t0);
  unsigned short* yp = yg + (size_t)t0 * DI + d;
  #pragma unroll 4
  for (int q = 0; q < CHL / 4; ++q) {
    float4 d4 = dp[q], u4 = up[q], B4 = Bp[q], C4 = Cp[q], z4 = zp[q];
    float y0, y1, y2, y3, a, cc;
    a = __expf(d4.x * A); h = fmaf(a, h, d4.x * u4.x * B4.x); cc = h * C4.x;
    cc += __shfl_xor(cc, 1, 16); cc += __shfl_xor(cc, 2, 16);
    cc += __shfl_xor(cc, 4, 16); cc += __shfl_xor(cc, 8, 16);
    y0 = (cc + u4.x * Dpv) * z4.x;
    a = __expf(d4.y * A); h = fmaf(a, h, d4.y * u4.y * B4.y); cc = h * C4.y;
    cc += __shfl_xor(cc, 1, 16); cc += __shfl_xor(cc, 2, 16);
    cc += __shfl_xor(cc, 4, 16); cc += __shfl_xor(cc, 8, 16);
    y1 = (cc + u4.y * Dpv) * z4.y;
    a = __expf(d4.z * A); h = fmaf(a, h, d4.z * u4.z * B4.z); cc = h * C4.z;
    cc += __shfl_xor(cc, 1, 16); cc += __shfl_xor(cc, 2, 16);
    cc += __shfl_xor(cc, 4, 16); cc += __shfl_xor(cc, 8, 16);
    y2 = (cc + u4.z * Dpv) * z4.z;
    a = __expf(d4.w * A); h = fmaf(a, h, d4.w * u4.w * B4.w); cc = h * C4.w;
    cc += __shfl_xor(cc, 1, 16); cc += __shfl_xor(cc, 2, 16);
    cc += __shfl_xor(cc, 4, 16); cc += __shfl_xor(cc, 8, 16);
    y3 = (cc + u4.w * Dpv) * z4.w;
    if (n == 0) {
      yp[(size_t)(q * 4 + 0) * DI] = f2b(y0);
      yp[(size_t)(q * 4 + 1) * DI] = f2b(y1);
      yp[(size_t)(q * 4 + 2) * DI] = f2b(y2);
      yp[(size_t)(q * 4 + 3) * DI] = f2b(y3);
    }
  }
}

// ---------------------------------------------------------------------------
// Fused LSE-reduce + label-dot: per row nll*mask and mask.  Grid T_TOK/4,
// 256 threads = 4 waves, one row per wave.
__global__ __launch_bounds__(256) void lse_label_kernel(
    const float* __restrict__ pmax, const float* __restrict__ psum,
    const unsigned short* __restrict__ h, const unsigned short* __restrict__ eb,
    const int* __restrict__ qids, const int* __restrict__ qmask,
    const int* __restrict__ aids, const int* __restrict__ amask,
    float* __restrict__ nllm, float* __restrict__ mrow) {
  int row = blockIdx.x * 4 + (threadIdx.x >> 6);
  int lane = threadIdx.x & 63;
  const float* pm = pmax + (size_t)row * NTILE_V;
  const float* ps = psum + (size_t)row * NTILE_V;
  float m = -INFINITY;
  for (int j = lane; j < NTILE_V; j += 64) m = fmaxf(m, pm[j]);
  for (int o = 1; o < 64; o <<= 1) m = fmaxf(m, __shfl_xor(m, o));
  float s = 0.f;
  for (int j = lane; j < NTILE_V; j += 64) s += ps[j] * __expf(pm[j] - m);
  for (int o = 1; o < 64; o <<= 1) s += __shfl_xor(s, o);
  float lse = m + __logf(s);
  int pos = row & 511, seq = row >> 9;
  float nll = 0.f, mv = 0.f;
  if (pos != 511) {
    const int* ids = (seq < 2) ? qids : aids;
    const int* msk = (seq < 2) ? qmask : amask;
    int lbl = ids[(seq & 1) * SEQL + pos + 1];
    mv = (float)msk[(seq & 1) * SEQL + pos + 1];
    const unsigned short* hr = h + (size_t)row * DM;
    const unsigned short* er = eb + (size_t)lbl * DM;
    float dt = 0.f;
    for (int k = lane; k < DM; k += 64) dt += b2f(hr[k]) * b2f(er[k]);
    for (int o = 1; o < 64; o <<= 1) dt += __shfl_xor(dt, o);
    nll = (lse - dt) * mv;
  }
  if (lane == 0) { nllm[row] = nll; mrow[row] = mv; }
}

// ---------------------------------------------------------------------------
// Final loss reduce
__global__ __launch_bounds__(256) void loss2_kernel(
    const float* __restrict__ nllm, const float* __restrict__ mrow,
    float* __restrict__ out) {
  float nq = 0.f, dq = 0.f, na = 0.f, da = 0.f;
  for (int row = threadIdx.x; row < T_TOK; row += 256) {
    int seq = row >> 9;
    if (seq < 2) { nq += nllm[row]; dq += mrow[row]; }
    else         { na += nllm[row]; da += mrow[row]; }
  }
  for (int o = 1; o < 64; o <<= 1) {
    nq += __shfl_xor(nq, o); dq += __shfl_xor(dq, o);
    na += __shfl_xor(na, o); da += __shfl_xor(da, o);
  }
  __shared__ float red[4][4];
  int w = threadIdx.x >> 6;
  if ((threadIdx.x & 63) == 0) { red[w][0] = nq; red[w][1] = dq; red[w][2] = na; red[w][3] = da; }
  __syncthreads();
  if (threadIdx.x == 0) {
    nq = 0.f; dq = 0.f; na = 0.f; da = 0.f;
    for (int i = 0; i < 4; ++i) { nq += red[i][0]; dq += red[i][1]; na += red[i][2]; da += red[i][3]; }
    float lq = nq / fmaxf(dq, 1.f);
    float la = na / fmaxf(da, 1.f);
    out[0] = lq + la;
  }
}

// ===========================================================================
extern "C" void kernel_launch(void* const* d_in, const int* in_sizes, int n_in,
                              void* d_out, int out_size, void* d_ws, size_t ws_size,
                              hipStream_t stream) {
  const int*   qids  = (const int*)d_in[0];
  const int*   qmask = (const int*)d_in[1];
  const int*   aids  = (const int*)d_in[2];
  const int*   amask = (const int*)d_in[3];
  const float* embed = (const float*)d_in[4];
  const float* ipw   = (const float*)d_in[5];
  const float* cw    = (const float*)d_in[6];
  const float* cb    = (const float*)d_in[7];
  const float* xpw   = (const float*)d_in[8];
  const float* dtw   = (const float*)d_in[9];
  const float* dtb   = (const float*)d_in[10];
  const float* Alog  = (const float*)d_in[11];
  const float* Dp    = (const float*)d_in[12];
  const float* opw   = (const float*)d_in[13];
  const float* nw    = (const float*)d_in[14];
  const float* nfw   = (const float*)d_in[15];

  char* wp = (char*)d_ws;
  auto alloc = [&](size_t bytes) { char* p = wp; wp += (bytes + 255) & ~(size_t)255; return p; };

  float*          x      = (float*)alloc((size_t)T_TOK * DM * 4);
  unsigned short* hbf    = (unsigned short*)alloc((size_t)T_TOK * DM * 2);
  float*          ur     = (float*)alloc((size_t)T_TOK * DI * 4);
  unsigned short* ucbf   = (unsigned short*)alloc((size_t)T_TOK * DI * 2);
  unsigned short* ygbf   = (unsigned short*)alloc((size_t)T_TOK * DI * 2);
  float*          ucT    = (float*)alloc((size_t)DI * T_TOK * 4);
  float*          zsT    = (float*)alloc((size_t)DI * T_TOK * 4);
  float*          dtT    = (float*)alloc((size_t)DI * T_TOK * 4);
  float*          BCt    = (float*)alloc((size_t)2 * NST * T_TOK * 4);
  float*          Pbuf   = (float*)alloc((size_t)4 * NCHUNK * DI * NST * 4);
  float*          Fbuf   = (float*)alloc((size_t)4 * NCHUNK * DI * NST * 4);
  float*          opart  = (float*)alloc((size_t)4 * T_TOK * DM * 4);
  unsigned short* ipw_t  = (unsigned short*)alloc((size_t)NLAYER * 2 * DI * DM * 2);
  unsigned short* opw_t  = (unsigned short*)alloc((size_t)NLAYER * DM * DI * 2);
  unsigned short* wcat   = (unsigned short*)alloc((size_t)NLAYER * NCAT * DI * 2);
  unsigned short* embbf  = (unsigned short*)alloc((size_t)VOCAB * DM * 2);
  float*          pmax   = (float*)alloc((size_t)T_TOK * NTILE_V * 4);
  float*          psum   = (float*)alloc((size_t)T_TOK * NTILE_V * 4);
  float*          nllm   = (float*)alloc((size_t)T_TOK * 4);
  float*          mrow   = (float*)alloc((size_t)T_TOK * 4);

  // One-time weight prep
  transpose_conv_kernel<<<dim3(96, 24, NLAYER), 256, 0, stream>>>(ipw, ipw_t, DM, 2 * DI, DM);
  transpose_conv_kernel<<<dim3(24, 48, NLAYER), 256, 0, stream>>>(opw, opw_t, DI, DM, DI);
  cvt_embed_kernel<<<2048, 256, 0, stream>>>(embed, embbf);
  wcat_bc_kernel<<<dim3(192, NLAYER), 256, 0, stream>>>(xpw, wcat);
  wdt_kernel<<<dim3(24, 24, NLAYER), 256, 0, stream>>>(xpw, dtw, wcat);

  // Embedding gather + layer-0 RMSNorm
  gather_rms_kernel<<<T_TOK, 256, 0, stream>>>(qids, qmask, aids, amask, embed, nw, x, hbf);

  const int mt = T_TOK / 128;  // 16 m-tiles
  for (int l = 0; l < NLAYER; ++l) {
    // in_proj (wide): u -> ur [t][DI], silu(z) -> zsT [ch][t]
    gemm_wide_kernel<7><<<mt * 12, 512, 0, stream>>>(
        hbf, DM, ipw_t + (size_t)l * 2 * DI * DM, DM, ur, zsT, nullptr,
        2 * DI, DM, mt);
    // conv + silu(u): ucbf [t][ch], ucT [ch][t]
    conv_silu_kernel<<<dim3(T_TOK / 64, DI / 64), 256, 0, stream>>>(
        ur, cw + (size_t)l * DI * KCONV, cb + (size_t)l * DI, ucbf, ucT);
    // fused BC + dt GEMM (wide): BCt [32][t], dtT [DI][t]
    gemm_wide_kernel<8><<<mt * 7, 512, 0, stream>>>(
        ucbf, DI, wcat + (size_t)l * NCAT * DI, DI, BCt, dtT,
        dtb + (size_t)l * DI, NCAT, DI, mt);
    // chunked parallel scan + fused gate
    scan_sum_kernel<<<32 * 96, 256, 0, stream>>>(
        dtT, ucT, BCt, Alog + (size_t)l * DI * NST, Pbuf, Fbuf);
    scan_emit_kernel<<<32 * 96, 256, 0, stream>>>(
        dtT, ucT, BCt, zsT, Alog + (size_t)l * DI * NST, Dp + (size_t)l * DI,
        Pbuf, Fbuf, ygbf);
    // out_proj split-K=4 partials (narrow)
    gemm_bf16_kernel<6><<<mt * (DM / 128) * 4, 256, 0, stream>>>(
        ygbf, DI, opw_t + (size_t)l * DM * DI, DI, opart, DM,
        T_TOK, DM, DI / 4, mt);
    // x += sum(opart); h = rms(x) * w_next  (nfw after last layer)
    resid_rms_kernel<<<T_TOK, 256, 0, stream>>>(
        x, opart, (l < NLAYER - 1) ? (nw + (l + 1) * DM) : nfw, hbf);
  }

  // Fused logits/LSE + loss
  gemm_lse_kernel<<<mt * NTILE_V, 512, 0, stream>>>(hbf, embbf, pmax, psum, mt);
  lse_label_kernel<<<T_TOK / 4, 256, 0, stream>>>(
      pmax, psum, hbf, embbf, qids, qmask, aids, amask, nllm, mrow);
  loss2_kernel<<<1, 256, 0, stream>>>(nllm, mrow, (float*)d_out);
}

// Round 16
// 1181.119 us; speedup vs baseline: 1.0465x; 1.0465x over previous
//
#include <hip/hip_runtime.h>
#include <hip/hip_bf16.h>
#include <cstdint>
#include <cstddef>

// Problem constants
#define T_TOK   2048   // 4 sequences (2 question + 2 answer) x 512
#define DM      768
#define DI      1536
#define NST     16
#define RRANK   48
#define KCONV   4
#define VOCAB   50280
#define NLAYER  4
#define SEQL    512
#define NTILE_V 197    // ceil(50280/256)
#define NCHUNK  8      // time chunks per sequence
#define CHL     64     // chunk length
#define NCAT    1568   // 32 (B,C) + 1536 (dt) fused projection cols

typedef __bf16 bf16x8 __attribute__((ext_vector_type(8)));
typedef float  f32x4  __attribute__((ext_vector_type(4)));

__device__ inline unsigned short f2b(float f) {
  union { float f; unsigned u; } v; v.f = f;
  unsigned r = v.u + 0x7FFFu + ((v.u >> 16) & 1u);   // RNE
  return (unsigned short)(r >> 16);
}
__device__ inline float b2f(unsigned short h) {
  union { unsigned u; float f; } v; v.u = ((unsigned)h) << 16;
  return v.f;
}

// global -> LDS direct 16B async copy. LDS dest is wave-uniform base; HW
// scatters lane i to base + i*16.
__device__ inline void gload_lds16(const unsigned short* g, unsigned short* l) {
  __builtin_amdgcn_global_load_lds(
      (const __attribute__((address_space(1))) void*)g,
      (__attribute__((address_space(3))) void*)l, 16, 0, 0);
}

// ---------------------------------------------------------------------------
// Transpose-convert: src f32 [R][C] -> dst bf16 [C][Rpad] (zero pad r>=R).
__global__ __launch_bounds__(256) void transpose_conv_kernel(
    const float* __restrict__ src, unsigned short* __restrict__ dst,
    int R, int C, int Rpad) {
  __shared__ float tile[32][33];
  const float* s = src + (size_t)blockIdx.z * R * C;
  unsigned short* d = dst + (size_t)blockIdx.z * C * Rpad;
  int c0 = blockIdx.x * 32, r0 = blockIdx.y * 32;
  int tx = threadIdx.x & 31, ty = threadIdx.x >> 5; // ty 0..7
  #pragma unroll
  for (int i = 0; i < 32; i += 8) {
    int r = r0 + ty + i, c = c0 + tx;
    tile[ty + i][tx] = (r < R && c < C) ? s[(size_t)r * C + c] : 0.f;
  }
  __syncthreads();
  #pragma unroll
  for (int i = 0; i < 32; i += 8) {
    int c = c0 + ty + i, r = r0 + tx;
    if (c < C && r < Rpad) d[(size_t)c * Rpad + r] = f2b(tile[tx][ty + i]);
  }
}

// ---------------------------------------------------------------------------
// embed f32 -> bf16 (grid-stride)
__global__ __launch_bounds__(256) void cvt_embed_kernel(
    const float* __restrict__ e, unsigned short* __restrict__ eb) {
  const int n4 = VOCAB * DM / 4;
  for (int i = blockIdx.x * 256 + threadIdx.x; i < n4; i += gridDim.x * 256) {
    float4 f = *(const float4*)(e + (size_t)i * 4);
    union { unsigned long long u; unsigned short h[4]; } pk;
    pk.h[0] = f2b(f.x); pk.h[1] = f2b(f.y); pk.h[2] = f2b(f.z); pk.h[3] = f2b(f.w);
    *(unsigned long long*)(eb + (size_t)i * 4) = pk.u;
  }
}

// ---------------------------------------------------------------------------
// W_cat rows 0..31: copy xpw cols 48..79 transposed.  Grid (192, NL).
__global__ __launch_bounds__(256) void wcat_bc_kernel(
    const float* __restrict__ xpw, unsigned short* __restrict__ wcat) {
  int l = blockIdx.y;
  int idx = blockIdx.x * 256 + threadIdx.x;   // 32*1536
  int n = idx / DI, k = idx - n * DI;
  wcat[(size_t)l * NCAT * DI + (size_t)n * DI + k] =
      f2b(xpw[(size_t)l * DI * 80 + (size_t)k * 80 + 48 + n]);
}

// ---------------------------------------------------------------------------
// W_cat rows 32..1567: Wdt[k][d] = sum_r xpw[k][r]*dtw[r][d], stored [32+d][k].
// Grid (24 ktiles, 24 dtiles, NL), 64x64 tile per block.
__global__ __launch_bounds__(256) void wdt_kernel(
    const float* __restrict__ xpw, const float* __restrict__ dtw,
    unsigned short* __restrict__ wcat) {
  __shared__ float xs[64][49];
  __shared__ float ds[48][64];
  int l = blockIdx.z;
  int k0 = blockIdx.x * 64, n0 = blockIdx.y * 64;
  const float* xp = xpw + (size_t)l * DI * 80;
  const float* dp = dtw + (size_t)l * RRANK * DI;
  int tid = threadIdx.x;
  {
    int row = tid >> 2, cg = (tid & 3) * 12;
    #pragma unroll
    for (int c = 0; c < 12; ++c)
      xs[row][cg + c] = xp[(size_t)(k0 + row) * 80 + cg + c];
    int col = tid & 63, rb = tid >> 6;
    #pragma unroll
    for (int i = 0; i < 12; ++i)
      ds[rb + 4 * i][col] = dp[(size_t)(rb + 4 * i) * DI + n0 + col];
  }
  __syncthreads();
  int tx = tid & 63, ty = tid >> 6;
  float acc[16] = {};
  #pragma unroll 8
  for (int r = 0; r < 48; ++r) {
    float xv = xs[tx][r];
    #pragma unroll
    for (int i = 0; i < 16; ++i) acc[i] += xv * ds[r][ty + 4 * i];
  }
  unsigned short* wl = wcat + (size_t)l * NCAT * DI + (size_t)(32 + n0) * DI;
  #pragma unroll
  for (int i = 0; i < 16; ++i)
    wl[(size_t)(ty + 4 * i) * DI + k0 + tx] = f2b(acc[i]);
}

// ---------------------------------------------------------------------------
// Fused embedding gather + layer-0 RMSNorm.  Grid T_TOK blocks.
__global__ __launch_bounds__(256) void gather_rms_kernel(
    const int* __restrict__ qids, const int* __restrict__ qmask,
    const int* __restrict__ aids, const int* __restrict__ amask,
    const float* __restrict__ embed, const float* __restrict__ w,
    float* __restrict__ x, unsigned short* __restrict__ h) {
  int t = blockIdx.x;
  int seq = t >> 9, pos = t & 511;
  const int* ids = (seq < 2) ? qids : aids;
  const int* msk = (seq < 2) ? qmask : amask;
  int s2 = seq & 1;
  int id = ids[s2 * SEQL + pos];
  float m = (float)msk[s2 * SEQL + pos];
  const float* er = embed + (size_t)id * DM;
  float v[3], ss = 0.f;
  #pragma unroll
  for (int j = 0; j < 3; ++j) {
    int d = threadIdx.x + j * 256;
    float vv = er[d] * m;
    x[(size_t)t * DM + d] = vv;
    v[j] = vv; ss += vv * vv;
  }
  for (int o = 1; o < 64; o <<= 1) ss += __shfl_xor(ss, o);
  __shared__ float wsum[4];
  if ((threadIdx.x & 63) == 0) wsum[threadIdx.x >> 6] = ss;
  __syncthreads();
  ss = wsum[0] + wsum[1] + wsum[2] + wsum[3];
  float sc = rsqrtf(ss / (float)DM + 1e-5f);
  #pragma unroll
  for (int j = 0; j < 3; ++j) {
    int d = threadIdx.x + j * 256;
    h[(size_t)t * DM + d] = f2b(v[j] * sc * w[d]);
  }
}

// ---------------------------------------------------------------------------
// Fused: x += sum(out_proj partials); h = rms(x)*w  (next layer / final norm)
__global__ __launch_bounds__(256) void resid_rms_kernel(
    float* __restrict__ x, const float* __restrict__ part,
    const float* __restrict__ w, unsigned short* __restrict__ h) {
  int t = blockIdx.x;
  float v[3];
  float ss = 0.f;
  #pragma unroll
  for (int j = 0; j < 3; ++j) {
    int d = threadIdx.x + j * 256;
    size_t o = (size_t)t * DM + d;
    float xv = x[o] + part[o] + part[(size_t)T_TOK * DM + o] +
               part[(size_t)2 * T_TOK * DM + o] + part[(size_t)3 * T_TOK * DM + o];
    x[o] = xv; v[j] = xv; ss += xv * xv;
  }
  for (int o = 1; o < 64; o <<= 1) ss += __shfl_xor(ss, o);
  __shared__ float wsum[4];
  if ((threadIdx.x & 63) == 0) wsum[threadIdx.x >> 6] = ss;
  __syncthreads();
  ss = wsum[0] + wsum[1] + wsum[2] + wsum[3];
  float sc = rsqrtf(ss / (float)DM + 1e-5f);
  #pragma unroll
  for (int j = 0; j < 3; ++j) {
    int d = threadIdx.x + j * 256;
    h[(size_t)t * DM + d] = f2b(v[j] * sc * w[d]);
  }
}

// ---------------------------------------------------------------------------
// Narrow GEMM: 128x128 tile, 4 waves, single-buffered + XOR-swizzle (m97).
// EPI 6 = split-K partial: C[(split*M+row)*ldc+col]
// EPI 7 = in_proj: col<DI -> C[row*DI+col]=u raw; col>=DI -> silu ->
//         CT[(col-DI)*T_TOK+row] transposed float4
// EPI 8 = fused BC/dt: col<32 -> C(BCt)[col*T_TOK+row] float4;
//         32<=col<NCAT -> softplus(acc+bias[col-32]) -> CT(dtT) float4
template <int EPI>
__global__ __launch_bounds__(256) void gemm_bf16_kernel(
    const unsigned short* __restrict__ A, int lda,
    const unsigned short* __restrict__ B, int ldb,
    float* __restrict__ C, float* __restrict__ CT, int ldc,
    const float* __restrict__ bias,
    int M, int N, int K, int mtiles) {
  __shared__ __attribute__((aligned(16))) unsigned short As[128 * 64];
  __shared__ __attribute__((aligned(16))) unsigned short Bs[128 * 64];
  int bid = blockIdx.x;
  int m0 = (bid % mtiles) * 128;
  int rest = bid / mtiles;
  int n0, split = 0;
  int ntil = (N + 127) >> 7;
  if (EPI == 6) { split = rest / ntil; n0 = (rest % ntil) * 128; }
  else n0 = rest * 128;
  const unsigned short* Ap = (EPI == 6) ? A + (size_t)split * K : A;
  const unsigned short* Bp = (EPI == 6) ? B + (size_t)split * K : B;
  int tid = threadIdx.x;
  int lane = tid & 63, w = tid >> 6;
  int wr = w >> 1, wc = w & 1;
  f32x4 acc[4][4] = {};

  int lrow = lane >> 3;                               // 0..7
  int lcol = (((lane & 7) ^ (lrow & 7)) & 7) * 8;     // pre-swizzled src chunk
  auto STAGE = [&](int k0) {
    #pragma unroll
    for (int it = 0; it < 4; ++it) {
      int r = w * 32 + it * 8;     // wave-uniform LDS row base
      gload_lds16(Ap + (size_t)(m0 + r + lrow) * lda + k0 + lcol, &As[r * 64]);
      int br = n0 + r + lrow; if (br > N - 1) br = N - 1;
      gload_lds16(Bp + (size_t)br * ldb + k0 + lcol, &Bs[r * 64]);
    }
  };

  int nst = K / 64;
  int rA = wr * 64 + (lane & 15);
  int rB = wc * 64 + (lane & 15);
  int sw = lane & 7, ckb = lane >> 4;
  for (int s = 0; s < nst; ++s) {
    STAGE(s * 64);
    __syncthreads();
    __builtin_amdgcn_s_setprio(1);
    #pragma unroll
    for (int ks = 0; ks < 2; ++ks) {
      int ca = (((ks * 4 + ckb) ^ sw) & 7) * 8;       // swizzled read chunk
      bf16x8 a[4], b[4];
      #pragma unroll
      for (int i = 0; i < 4; ++i) a[i] = *(const bf16x8*)(&As[(rA + i * 16) * 64 + ca]);
      #pragma unroll
      for (int i = 0; i < 4; ++i) b[i] = *(const bf16x8*)(&Bs[(rB + i * 16) * 64 + ca]);
      #pragma unroll
      for (int mi = 0; mi < 4; ++mi)
        #pragma unroll
        for (int ni = 0; ni < 4; ++ni)
          acc[mi][ni] = __builtin_amdgcn_mfma_f32_16x16x32_bf16(a[mi], b[ni], acc[mi][ni], 0, 0, 0);
    }
    __builtin_amdgcn_s_setprio(0);
    __syncthreads();
  }

  int g = lane >> 4, c = lane & 15;
  #pragma unroll
  for (int mi = 0; mi < 4; ++mi)
    #pragma unroll
    for (int ni = 0; ni < 4; ++ni) {
      int col = n0 + wc * 64 + ni * 16 + c;
      int row0 = m0 + wr * 64 + mi * 16 + g * 4;
      if (EPI == 6) {
        if (col < N) {
          #pragma unroll
          for (int r = 0; r < 4; ++r)
            C[((size_t)split * M + row0 + r) * ldc + col] = acc[mi][ni][r];
        }
      }
      if (EPI == 7) {
        if (col < DI) {
          #pragma unroll
          for (int r = 0; r < 4; ++r)
            C[(size_t)(row0 + r) * DI + col] = acc[mi][ni][r];
        } else {
          float4 o; float* ov = (float*)&o;
          #pragma unroll
          for (int r = 0; r < 4; ++r) {
            float zv = acc[mi][ni][r];
            ov[r] = zv / (1.f + __expf(-zv));
          }
          *(float4*)(&CT[(size_t)(col - DI) * T_TOK + row0]) = o;
        }
      }
      if (EPI == 8) {
        if (col < 32) {
          float4 o; float* ov = (float*)&o;
          #pragma unroll
          for (int r = 0; r < 4; ++r) ov[r] = acc[mi][ni][r];
          *(float4*)(&C[(size_t)col * T_TOK + row0]) = o;
        } else if (col < NCAT) {
          float4 o; float* ov = (float*)&o;
          #pragma unroll
          for (int r = 0; r < 4; ++r) {
            float xv = acc[mi][ni][r] + bias[col - 32];
            ov[r] = (xv > 20.f) ? xv : log1pf(__expf(xv));
          }
          *(float4*)(&CT[(size_t)(col - 32) * T_TOK + row0]) = o;
        }
      }
    }
}

// ---------------------------------------------------------------------------
// Logits GEMM + fused LSE partials.  128x256 tile, 8 waves (R11, unchanged).
__global__ __launch_bounds__(512) void gemm_lse_kernel(
    const unsigned short* __restrict__ A,
    const unsigned short* __restrict__ B,
    float* __restrict__ pmax, float* __restrict__ psum,
    int mtiles) {
  __shared__ __attribute__((aligned(16))) unsigned short As[128 * 64];
  __shared__ __attribute__((aligned(16))) unsigned short Bs[256 * 64];
  __shared__ float lmax[128][4];
  __shared__ float lsum[128][4];
  const int K = DM, Nv = VOCAB;
  int bid = blockIdx.x;
  int m0 = (bid % mtiles) * 128;
  int n0 = (bid / mtiles) * 256;
  int tid = threadIdx.x;
  int lane = tid & 63, w = tid >> 6;   // 8 waves
  int wr = w >> 2, wc = w & 3;         // 2 x 4; per-wave output 64x64
  f32x4 acc[4][4] = {};

  int lrow = lane >> 3;
  int lcol = (((lane & 7) ^ (lrow & 7)) & 7) * 8;   // pre-swizzled src chunk
  auto STAGE = [&](int k0) {
    #pragma unroll
    for (int it = 0; it < 2; ++it) {            // A: 8 waves x 16 rows
      int r = w * 16 + it * 8;
      gload_lds16(A + (size_t)(m0 + r + lrow) * K + k0 + lcol, &As[r * 64]);
    }
    #pragma unroll
    for (int it = 0; it < 4; ++it) {            // B: 8 waves x 32 rows
      int r = w * 32 + it * 8;
      int br = n0 + r + lrow; if (br > Nv - 1) br = Nv - 1;
      gload_lds16(B + (size_t)br * K + k0 + lcol, &Bs[r * 64]);
    }
  };

  const int nst = K / 64;   // 12
  int rA = wr * 64 + (lane & 15);
  int rB = wc * 64 + (lane & 15);
  int sw = lane & 7, ckb = lane >> 4;
  for (int s = 0; s < nst; ++s) {
    STAGE(s * 64);
    __syncthreads();
    __builtin_amdgcn_s_setprio(1);
    #pragma unroll
    for (int ks = 0; ks < 2; ++ks) {
      int ca = (((ks * 4 + ckb) ^ sw) & 7) * 8;
      bf16x8 a[4], b[4];
      #pragma unroll
      for (int i = 0; i < 4; ++i) a[i] = *(const bf16x8*)(&As[(rA + i * 16) * 64 + ca]);
      #pragma unroll
      for (int i = 0; i < 4; ++i) b[i] = *(const bf16x8*)(&Bs[(rB + i * 16) * 64 + ca]);
      #pragma unroll
      for (int mi = 0; mi < 4; ++mi)
        #pragma unroll
        for (int ni = 0; ni < 4; ++ni)
          acc[mi][ni] = __builtin_amdgcn_mfma_f32_16x16x32_bf16(a[mi], b[ni], acc[mi][ni], 0, 0, 0);
    }
    __builtin_amdgcn_s_setprio(0);
    __syncthreads();
  }

  // Row-wise (max, sum exp) over this block's 256 columns (4 wc groups).
  int g = lane >> 4, c = lane & 15;
  #pragma unroll
  for (int mi = 0; mi < 4; ++mi) {
    #pragma unroll
    for (int r = 0; r < 4; ++r) {
      float mx = -INFINITY;
      #pragma unroll
      for (int ni = 0; ni < 4; ++ni) {
        int col = n0 + wc * 64 + ni * 16 + c;
        float v = (col < Nv) ? acc[mi][ni][r] : -INFINITY;
        mx = fmaxf(mx, v);
      }
      mx = fmaxf(mx, __shfl_xor(mx, 1, 16));
      mx = fmaxf(mx, __shfl_xor(mx, 2, 16));
      mx = fmaxf(mx, __shfl_xor(mx, 4, 16));
      mx = fmaxf(mx, __shfl_xor(mx, 8, 16));
      float ssum = 0.f;
      #pragma unroll
      for (int ni = 0; ni < 4; ++ni) {
        int col = n0 + wc * 64 + ni * 16 + c;
        if (col < Nv) ssum += __expf(acc[mi][ni][r] - mx);
      }
      ssum += __shfl_xor(ssum, 1, 16);
      ssum += __shfl_xor(ssum, 2, 16);
      ssum += __shfl_xor(ssum, 4, 16);
      ssum += __shfl_xor(ssum, 8, 16);
      if (c == 0) {
        int rl = wr * 64 + mi * 16 + g * 4 + r;
        lmax[rl][wc] = mx;
        lsum[rl][wc] = ssum;
      }
    }
  }
  __syncthreads();
  if (tid < 128) {
    float m0v = lmax[tid][0], m1 = lmax[tid][1], m2 = lmax[tid][2], m3 = lmax[tid][3];
    float Mx = fmaxf(fmaxf(m0v, m1), fmaxf(m2, m3));
    float S = lsum[tid][0] * __expf(m0v - Mx) + lsum[tid][1] * __expf(m1 - Mx) +
              lsum[tid][2] * __expf(m2 - Mx) + lsum[tid][3] * __expf(m3 - Mx);
    int row = m0 + tid;
    int nb = n0 >> 8;
    pmax[(size_t)row * NTILE_V + nb] = Mx;
    psum[(size_t)row * NTILE_V + nb] = S;
  }
}

// ---------------------------------------------------------------------------
// Tiled causal depthwise conv (K=4) + silu on u only.
__global__ __launch_bounds__(256) void conv_silu_kernel(
    const float* __restrict__ ur, const float* __restrict__ cw,
    const float* __restrict__ cb,
    unsigned short* __restrict__ ucbf, float* __restrict__ ucT) {
  __shared__ float xu[67][64];
  __shared__ float ou[64][65];
  int t0 = blockIdx.x * 64;
  int ch0 = blockIdx.y * 64;
  int tid = threadIdx.x;
  int cx = tid & 63, ty = tid >> 6;           // ty 0..3
  bool seq_start = (t0 & 511) == 0;
  for (int r = ty; r < 67; r += 4) {
    int tg = t0 - 3 + r;
    float v = 0.f;
    if (r >= 3 || !seq_start) v = ur[(size_t)tg * DI + ch0 + cx];
    xu[r][cx] = v;
  }
  __syncthreads();
  int ch = ch0 + cx;
  float4 wv = *(const float4*)(cw + ch * 4);
  float bias = cb[ch];
  #pragma unroll
  for (int i = 0; i < 16; ++i) {
    int tr = ty * 16 + i;
    float a = bias + xu[tr][cx] * wv.x + xu[tr + 1][cx] * wv.y +
              xu[tr + 2][cx] * wv.z + xu[tr + 3][cx] * wv.w;
    float s = a / (1.f + __expf(-a));
    ucbf[(size_t)(t0 + tr) * DI + ch] = f2b(s);
    ou[tr][cx] = s;
  }
  __syncthreads();
  int tx = tid & 63, cy = tid >> 6;
  #pragma unroll
  for (int i = 0; i < 16; ++i) {
    int chi = cy * 16 + i;
    ucT[(size_t)(ch0 + chi) * T_TOK + t0 + tx] = ou[tx][chi];
  }
}

// ---------------------------------------------------------------------------
// Scan phase 1: per-(b,d,n,chunk) summary.
__global__ __launch_bounds__(256) void scan_sum_kernel(
    const float* __restrict__ dtT, const float* __restrict__ ucT,
    const float* __restrict__ BCt, const float* __restrict__ Alog,
    float* __restrict__ Pbuf, float* __restrict__ Fbuf) {
  int bc = blockIdx.x / 96;                 // b*8+chunk
  int idx = (blockIdx.x % 96) * 256 + threadIdx.x;
  int n = idx & 15, d = idx >> 4;
  int b = bc >> 3, chunk = bc & 7;
  float A = -__expf(Alog[d * NST + n]);
  int t0 = b * SEQL + chunk * CHL;
  const float4* dp = (const float4*)(dtT + (size_t)d * T_TOK + t0);
  const float4* up = (const float4*)(ucT + (size_t)d * T_TOK + t0);
  const float4* Bp = (const float4*)(BCt + (size_t)n * T_TOK + t0);
  float h = 0.f, sdt = 0.f;
  #pragma unroll
  for (int q = 0; q < CHL / 4; ++q) {
    float4 d4 = dp[q], u4 = up[q], B4 = Bp[q];
    float a;
    a = __expf(d4.x * A); h = fmaf(a, h, d4.x * u4.x * B4.x);
    a = __expf(d4.y * A); h = fmaf(a, h, d4.y * u4.y * B4.y);
    a = __expf(d4.z * A); h = fmaf(a, h, d4.z * u4.z * B4.z);
    a = __expf(d4.w * A); h = fmaf(a, h, d4.w * u4.w * B4.w);
    sdt += d4.x + d4.y + d4.z + d4.w;
  }
  size_t s = ((size_t)bc * DI + d) * NST + n;
  Pbuf[s] = __expf(A * sdt);
  Fbuf[s] = h;
}

// ---------------------------------------------------------------------------
// Scan phase 3 + fused gate.
__global__ __launch_bounds__(256) void scan_emit_kernel(
    const float* __restrict__ dtT, const float* __restrict__ ucT,
    const float* __restrict__ BCt, const float* __restrict__ zsT,
    const float* __restrict__ Alog, const float* __restrict__ Dpar,
    const float* __restrict__ Pbuf, const float* __restrict__ Fbuf,
    unsigned short* __restrict__ yg) {
  int bc = blockIdx.x / 96;                 // b*8+chunk
  int idx = (blockIdx.x % 96) * 256 + threadIdx.x;
  int n = idx & 15, d = idx >> 4;
  int b = bc >> 3, chunk = bc & 7;
  float A = -__expf(Alog[d * NST + n]);
  float Dpv = Dpar[d];
  float h = 0.f;
  for (int j = 0; j < chunk; ++j) {
    size_t s = (((size_t)(b * NCHUNK + j)) * DI + d) * NST + n;
    h = Fbuf[s] + Pbuf[s] * h;
  }
  int t0 = b * SEQL + chunk * CHL;
  const float4* dp = (const float4*)(dtT + (size_t)d * T_TOK + t0);
  const float4* up = (const float4*)(ucT + (size_t)d * T_TOK + t0);
  const float4* Bp = (const float4*)(BCt + (size_t)n * T_TOK + t0);
  const float4* Cp = (const float4*)(BCt + (size_t)(NST + n) * T_TOK + t0);
  const float4* zp = (const float4*)(zsT + (size_t)d * T_TOK + t0);
  unsigned short* yp = yg + (size_t)t0 * DI + d;
  #pragma unroll 4
  for (int q = 0; q < CHL / 4; ++q) {
    float4 d4 = dp[q], u4 = up[q], B4 = Bp[q], C4 = Cp[q], z4 = zp[q];
    float y0, y1, y2, y3, a, cc;
    a = __expf(d4.x * A); h = fmaf(a, h, d4.x * u4.x * B4.x); cc = h * C4.x;
    cc += __shfl_xor(cc, 1, 16); cc += __shfl_xor(cc, 2, 16);
    cc += __shfl_xor(cc, 4, 16); cc += __shfl_xor(cc, 8, 16);
    y0 = (cc + u4.x * Dpv) * z4.x;
    a = __expf(d4.y * A); h = fmaf(a, h, d4.y * u4.y * B4.y); cc = h * C4.y;
    cc += __shfl_xor(cc, 1, 16); cc += __shfl_xor(cc, 2, 16);
    cc += __shfl_xor(cc, 4, 16); cc += __shfl_xor(cc, 8, 16);
    y1 = (cc + u4.y * Dpv) * z4.y;
    a = __expf(d4.z * A); h = fmaf(a, h, d4.z * u4.z * B4.z); cc = h * C4.z;
    cc += __shfl_xor(cc, 1, 16); cc += __shfl_xor(cc, 2, 16);
    cc += __shfl_xor(cc, 4, 16); cc += __shfl_xor(cc, 8, 16);
    y2 = (cc + u4.z * Dpv) * z4.z;
    a = __expf(d4.w * A); h = fmaf(a, h, d4.w * u4.w * B4.w); cc = h * C4.w;
    cc += __shfl_xor(cc, 1, 16); cc += __shfl_xor(cc, 2, 16);
    cc += __shfl_xor(cc, 4, 16); cc += __shfl_xor(cc, 8, 16);
    y3 = (cc + u4.w * Dpv) * z4.w;
    if (n == 0) {
      yp[(size_t)(q * 4 + 0) * DI] = f2b(y0);
      yp[(size_t)(q * 4 + 1) * DI] = f2b(y1);
      yp[(size_t)(q * 4 + 2) * DI] = f2b(y2);
      yp[(size_t)(q * 4 + 3) * DI] = f2b(y3);
    }
  }
}

// ---------------------------------------------------------------------------
// Fused LSE-reduce + label-dot: per row nll*mask and mask.  Grid T_TOK/4.
__global__ __launch_bounds__(256) void lse_label_kernel(
    const float* __restrict__ pmax, const float* __restrict__ psum,
    const unsigned short* __restrict__ h, const unsigned short* __restrict__ eb,
    const int* __restrict__ qids, const int* __restrict__ qmask,
    const int* __restrict__ aids, const int* __restrict__ amask,
    float* __restrict__ nllm, float* __restrict__ mrow) {
  int row = blockIdx.x * 4 + (threadIdx.x >> 6);
  int lane = threadIdx.x & 63;
  const float* pm = pmax + (size_t)row * NTILE_V;
  const float* ps = psum + (size_t)row * NTILE_V;
  float m = -INFINITY;
  for (int j = lane; j < NTILE_V; j += 64) m = fmaxf(m, pm[j]);
  for (int o = 1; o < 64; o <<= 1) m = fmaxf(m, __shfl_xor(m, o));
  float s = 0.f;
  for (int j = lane; j < NTILE_V; j += 64) s += ps[j] * __expf(pm[j] - m);
  for (int o = 1; o < 64; o <<= 1) s += __shfl_xor(s, o);
  float lse = m + __logf(s);
  int pos = row & 511, seq = row >> 9;
  float nll = 0.f, mv = 0.f;
  if (pos != 511) {
    const int* ids = (seq < 2) ? qids : aids;
    const int* msk = (seq < 2) ? qmask : amask;
    int lbl = ids[(seq & 1) * SEQL + pos + 1];
    mv = (float)msk[(seq & 1) * SEQL + pos + 1];
    const unsigned short* hr = h + (size_t)row * DM;
    const unsigned short* er = eb + (size_t)lbl * DM;
    float dt = 0.f;
    for (int k = lane; k < DM; k += 64) dt += b2f(hr[k]) * b2f(er[k]);
    for (int o = 1; o < 64; o <<= 1) dt += __shfl_xor(dt, o);
    nll = (lse - dt) * mv;
  }
  if (lane == 0) { nllm[row] = nll; mrow[row] = mv; }
}

// ---------------------------------------------------------------------------
// Final loss reduce
__global__ __launch_bounds__(256) void loss2_kernel(
    const float* __restrict__ nllm, const float* __restrict__ mrow,
    float* __restrict__ out) {
  float nq = 0.f, dq = 0.f, na = 0.f, da = 0.f;
  for (int row = threadIdx.x; row < T_TOK; row += 256) {
    int seq = row >> 9;
    if (seq < 2) { nq += nllm[row]; dq += mrow[row]; }
    else         { na += nllm[row]; da += mrow[row]; }
  }
  for (int o = 1; o < 64; o <<= 1) {
    nq += __shfl_xor(nq, o); dq += __shfl_xor(dq, o);
    na += __shfl_xor(na, o); da += __shfl_xor(da, o);
  }
  __shared__ float red[4][4];
  int w = threadIdx.x >> 6;
  if ((threadIdx.x & 63) == 0) { red[w][0] = nq; red[w][1] = dq; red[w][2] = na; red[w][3] = da; }
  __syncthreads();
  if (threadIdx.x == 0) {
    nq = 0.f; dq = 0.f; na = 0.f; da = 0.f;
    for (int i = 0; i < 4; ++i) { nq += red[i][0]; dq += red[i][1]; na += red[i][2]; da += red[i][3]; }
    float lq = nq / fmaxf(dq, 1.f);
    float la = na / fmaxf(da, 1.f);
    out[0] = lq + la;
  }
}

// ===========================================================================
extern "C" void kernel_launch(void* const* d_in, const int* in_sizes, int n_in,
                              void* d_out, int out_size, void* d_ws, size_t ws_size,
                              hipStream_t stream) {
  const int*   qids  = (const int*)d_in[0];
  const int*   qmask = (const int*)d_in[1];
  const int*   aids  = (const int*)d_in[2];
  const int*   amask = (const int*)d_in[3];
  const float* embed = (const float*)d_in[4];
  const float* ipw   = (const float*)d_in[5];
  const float* cw    = (const float*)d_in[6];
  const float* cb    = (const float*)d_in[7];
  const float* xpw   = (const float*)d_in[8];
  const float* dtw   = (const float*)d_in[9];
  const float* dtb   = (const float*)d_in[10];
  const float* Alog  = (const float*)d_in[11];
  const float* Dp    = (const float*)d_in[12];
  const float* opw   = (const float*)d_in[13];
  const float* nw    = (const float*)d_in[14];
  const float* nfw   = (const float*)d_in[15];

  char* wp = (char*)d_ws;
  auto alloc = [&](size_t bytes) { char* p = wp; wp += (bytes + 255) & ~(size_t)255; return p; };

  float*          x      = (float*)alloc((size_t)T_TOK * DM * 4);
  unsigned short* hbf    = (unsigned short*)alloc((size_t)T_TOK * DM * 2);
  float*          ur     = (float*)alloc((size_t)T_TOK * DI * 4);
  unsigned short* ucbf   = (unsigned short*)alloc((size_t)T_TOK * DI * 2);
  unsigned short* ygbf   = (unsigned short*)alloc((size_t)T_TOK * DI * 2);
  float*          ucT    = (float*)alloc((size_t)DI * T_TOK * 4);
  float*          zsT    = (float*)alloc((size_t)DI * T_TOK * 4);
  float*          dtT    = (float*)alloc((size_t)DI * T_TOK * 4);
  float*          BCt    = (float*)alloc((size_t)2 * NST * T_TOK * 4);
  float*          Pbuf   = (float*)alloc((size_t)4 * NCHUNK * DI * NST * 4);
  float*          Fbuf   = (float*)alloc((size_t)4 * NCHUNK * DI * NST * 4);
  float*          opart  = (float*)alloc((size_t)4 * T_TOK * DM * 4);
  unsigned short* ipw_t  = (unsigned short*)alloc((size_t)NLAYER * 2 * DI * DM * 2);
  unsigned short* opw_t  = (unsigned short*)alloc((size_t)NLAYER * DM * DI * 2);
  unsigned short* wcat   = (unsigned short*)alloc((size_t)NLAYER * NCAT * DI * 2);
  unsigned short* embbf  = (unsigned short*)alloc((size_t)VOCAB * DM * 2);
  float*          pmax   = (float*)alloc((size_t)T_TOK * NTILE_V * 4);
  float*          psum   = (float*)alloc((size_t)T_TOK * NTILE_V * 4);
  float*          nllm   = (float*)alloc((size_t)T_TOK * 4);
  float*          mrow   = (float*)alloc((size_t)T_TOK * 4);

  // One-time weight prep
  transpose_conv_kernel<<<dim3(96, 24, NLAYER), 256, 0, stream>>>(ipw, ipw_t, DM, 2 * DI, DM);
  transpose_conv_kernel<<<dim3(24, 48, NLAYER), 256, 0, stream>>>(opw, opw_t, DI, DM, DI);
  cvt_embed_kernel<<<2048, 256, 0, stream>>>(embed, embbf);
  wcat_bc_kernel<<<dim3(192, NLAYER), 256, 0, stream>>>(xpw, wcat);
  wdt_kernel<<<dim3(24, 24, NLAYER), 256, 0, stream>>>(xpw, dtw, wcat);

  // Embedding gather + layer-0 RMSNorm
  gather_rms_kernel<<<T_TOK, 256, 0, stream>>>(qids, qmask, aids, amask, embed, nw, x, hbf);

  const int mt = T_TOK / 128;  // 16 m-tiles
  for (int l = 0; l < NLAYER; ++l) {
    // in_proj (narrow, 384 blocks): u -> ur [t][DI], silu(z) -> zsT [ch][t]
    gemm_bf16_kernel<7><<<mt * (2 * DI / 128), 256, 0, stream>>>(
        hbf, DM, ipw_t + (size_t)l * 2 * DI * DM, DM, ur, zsT, DI,
        nullptr, T_TOK, 2 * DI, DM, mt);
    // conv + silu(u): ucbf [t][ch], ucT [ch][t]
    conv_silu_kernel<<<dim3(T_TOK / 64, DI / 64), 256, 0, stream>>>(
        ur, cw + (size_t)l * DI * KCONV, cb + (size_t)l * DI, ucbf, ucT);
    // fused BC + dt GEMM (narrow, 208 blocks): BCt [32][t], dtT [DI][t]
    gemm_bf16_kernel<8><<<mt * 13, 256, 0, stream>>>(
        ucbf, DI, wcat + (size_t)l * NCAT * DI, DI, BCt, dtT, 0,
        dtb + (size_t)l * DI, T_TOK, NCAT, DI, mt);
    // chunked parallel scan + fused gate
    scan_sum_kernel<<<32 * 96, 256, 0, stream>>>(
        dtT, ucT, BCt, Alog + (size_t)l * DI * NST, Pbuf, Fbuf);
    scan_emit_kernel<<<32 * 96, 256, 0, stream>>>(
        dtT, ucT, BCt, zsT, Alog + (size_t)l * DI * NST, Dp + (size_t)l * DI,
        Pbuf, Fbuf, ygbf);
    // out_proj split-K=4 partials (narrow, 384 blocks)
    gemm_bf16_kernel<6><<<mt * (DM / 128) * 4, 256, 0, stream>>>(
        ygbf, DI, opw_t + (size_t)l * DM * DI, DI, opart, nullptr, DM,
        nullptr, T_TOK, DM, DI / 4, mt);
    // x += sum(opart); h = rms(x) * w_next  (nfw after last layer)
    resid_rms_kernel<<<T_TOK, 256, 0, stream>>>(
        x, opart, (l < NLAYER - 1) ? (nw + (l + 1) * DM) : nfw, hbf);
  }

  // Fused logits/LSE + loss
  gemm_lse_kernel<<<mt * NTILE_V, 512, 0, stream>>>(hbf, embbf, pmax, psum, mt);
  lse_label_kernel<<<T_TOK / 4, 256, 0, stream>>>(
      pmax, psum, hbf, embbf, qids, qmask, aids, amask, nllm, mrow);
  loss2_kernel<<<1, 256, 0, stream>>>(nllm, mrow, (float*)d_out);
}

// Round 17
// 1114.739 us; speedup vs baseline: 1.1088x; 1.0595x over previous
//
#include <hip/hip_runtime.h>
#include <hip/hip_bf16.h>
#include <cstdint>
#include <cstddef>

// Problem constants
#define T_TOK   2048   // 4 sequences (2 question + 2 answer) x 512
#define DM      768
#define DI      1536
#define NST     16
#define RRANK   48
#define KCONV   4
#define VOCAB   50280
#define NLAYER  4
#define SEQL    512
#define NTILE_V 197    // ceil(50280/256)
#define NCHUNK  8      // time chunks per sequence
#define CHL     64     // chunk length

typedef __bf16 bf16x8 __attribute__((ext_vector_type(8)));
typedef float  f32x4  __attribute__((ext_vector_type(4)));

__device__ inline unsigned short f2b(float f) {
  union { float f; unsigned u; } v; v.f = f;
  unsigned r = v.u + 0x7FFFu + ((v.u >> 16) & 1u);   // RNE
  return (unsigned short)(r >> 16);
}
__device__ inline float b2f(unsigned short h) {
  union { unsigned u; float f; } v; v.u = ((unsigned)h) << 16;
  return v.f;
}

// global -> LDS direct 16B async copy. LDS dest is wave-uniform base; HW
// scatters lane i to base + i*16.
__device__ inline void gload_lds16(const unsigned short* g, unsigned short* l) {
  __builtin_amdgcn_global_load_lds(
      (const __attribute__((address_space(1))) void*)g,
      (__attribute__((address_space(3))) void*)l, 16, 0, 0);
}

// ---------------------------------------------------------------------------
// Transpose-convert: src f32 [R][C] -> dst bf16 [C][Rpad] (zero pad r>=R).
__global__ __launch_bounds__(256) void transpose_conv_kernel(
    const float* __restrict__ src, unsigned short* __restrict__ dst,
    int R, int C, int Rpad) {
  __shared__ float tile[32][33];
  const float* s = src + (size_t)blockIdx.z * R * C;
  unsigned short* d = dst + (size_t)blockIdx.z * C * Rpad;
  int c0 = blockIdx.x * 32, r0 = blockIdx.y * 32;
  int tx = threadIdx.x & 31, ty = threadIdx.x >> 5; // ty 0..7
  #pragma unroll
  for (int i = 0; i < 32; i += 8) {
    int r = r0 + ty + i, c = c0 + tx;
    tile[ty + i][tx] = (r < R && c < C) ? s[(size_t)r * C + c] : 0.f;
  }
  __syncthreads();
  #pragma unroll
  for (int i = 0; i < 32; i += 8) {
    int c = c0 + ty + i, r = r0 + tx;
    if (c < C && r < Rpad) d[(size_t)c * Rpad + r] = f2b(tile[tx][ty + i]);
  }
}

// ---------------------------------------------------------------------------
// embed f32 -> bf16 (grid-stride)
__global__ __launch_bounds__(256) void cvt_embed_kernel(
    const float* __restrict__ e, unsigned short* __restrict__ eb) {
  const int n4 = VOCAB * DM / 4;
  for (int i = blockIdx.x * 256 + threadIdx.x; i < n4; i += gridDim.x * 256) {
    float4 f = *(const float4*)(e + (size_t)i * 4);
    union { unsigned long long u; unsigned short h[4]; } pk;
    pk.h[0] = f2b(f.x); pk.h[1] = f2b(f.y); pk.h[2] = f2b(f.z); pk.h[3] = f2b(f.w);
    *(unsigned long long*)(eb + (size_t)i * 4) = pk.u;
  }
}

// ---------------------------------------------------------------------------
// Fused embedding gather + layer-0 RMSNorm.  Grid T_TOK blocks.
__global__ __launch_bounds__(256) void gather_rms_kernel(
    const int* __restrict__ qids, const int* __restrict__ qmask,
    const int* __restrict__ aids, const int* __restrict__ amask,
    const float* __restrict__ embed, const float* __restrict__ w,
    float* __restrict__ x, unsigned short* __restrict__ h) {
  int t = blockIdx.x;
  int seq = t >> 9, pos = t & 511;
  const int* ids = (seq < 2) ? qids : aids;
  const int* msk = (seq < 2) ? qmask : amask;
  int s2 = seq & 1;
  int id = ids[s2 * SEQL + pos];
  float m = (float)msk[s2 * SEQL + pos];
  const float* er = embed + (size_t)id * DM;
  float v[3], ss = 0.f;
  #pragma unroll
  for (int j = 0; j < 3; ++j) {
    int d = threadIdx.x + j * 256;
    float vv = er[d] * m;
    x[(size_t)t * DM + d] = vv;
    v[j] = vv; ss += vv * vv;
  }
  for (int o = 1; o < 64; o <<= 1) ss += __shfl_xor(ss, o);
  __shared__ float wsum[4];
  if ((threadIdx.x & 63) == 0) wsum[threadIdx.x >> 6] = ss;
  __syncthreads();
  ss = wsum[0] + wsum[1] + wsum[2] + wsum[3];
  float sc = rsqrtf(ss / (float)DM + 1e-5f);
  #pragma unroll
  for (int j = 0; j < 3; ++j) {
    int d = threadIdx.x + j * 256;
    h[(size_t)t * DM + d] = f2b(v[j] * sc * w[d]);
  }
}

// ---------------------------------------------------------------------------
// Fused: x += sum(out_proj partials); h = rms(x)*w  (next layer / final norm)
__global__ __launch_bounds__(256) void resid_rms_kernel(
    float* __restrict__ x, const float* __restrict__ part,
    const float* __restrict__ w, unsigned short* __restrict__ h) {
  int t = blockIdx.x;
  float v[3];
  float ss = 0.f;
  #pragma unroll
  for (int j = 0; j < 3; ++j) {
    int d = threadIdx.x + j * 256;
    size_t o = (size_t)t * DM + d;
    float xv = x[o] + part[o] + part[(size_t)T_TOK * DM + o] +
               part[(size_t)2 * T_TOK * DM + o] + part[(size_t)3 * T_TOK * DM + o];
    x[o] = xv; v[j] = xv; ss += xv * xv;
  }
  for (int o = 1; o < 64; o <<= 1) ss += __shfl_xor(ss, o);
  __shared__ float wsum[4];
  if ((threadIdx.x & 63) == 0) wsum[threadIdx.x >> 6] = ss;
  __syncthreads();
  ss = wsum[0] + wsum[1] + wsum[2] + wsum[3];
  float sc = rsqrtf(ss / (float)DM + 1e-5f);
  #pragma unroll
  for (int j = 0; j < 3; ++j) {
    int d = threadIdx.x + j * 256;
    h[(size_t)t * DM + d] = f2b(v[j] * sc * w[d]);
  }
}

// ---------------------------------------------------------------------------
// Narrow GEMM: 128x128 tile, 4 waves, single-buffered + XOR-swizzle (m97).
// EPI 5 = dt: softplus(acc+bias[col]) -> CT[col*T_TOK+row] float4
// EPI 6 = split-K partial: C[(split*M+row)*ldc+col]
// EPI 7 = in_proj: col<DI -> C[row*DI+col]=u raw; col>=DI -> silu ->
//         CT[(col-DI)*T_TOK+row] transposed float4
template <int EPI>
__global__ __launch_bounds__(256) void gemm_bf16_kernel(
    const unsigned short* __restrict__ A, int lda,
    const unsigned short* __restrict__ B, int ldb,
    float* __restrict__ C, float* __restrict__ CT, int ldc,
    const float* __restrict__ bias,
    int M, int N, int K, int mtiles) {
  __shared__ __attribute__((aligned(16))) unsigned short As[128 * 64];
  __shared__ __attribute__((aligned(16))) unsigned short Bs[128 * 64];
  int bid = blockIdx.x;
  int m0 = (bid % mtiles) * 128;
  int rest = bid / mtiles;
  int n0, split = 0;
  int ntil = (N + 127) >> 7;
  if (EPI == 6) { split = rest / ntil; n0 = (rest % ntil) * 128; }
  else n0 = rest * 128;
  const unsigned short* Ap = (EPI == 6) ? A + (size_t)split * K : A;
  const unsigned short* Bp = (EPI == 6) ? B + (size_t)split * K : B;
  int tid = threadIdx.x;
  int lane = tid & 63, w = tid >> 6;
  int wr = w >> 1, wc = w & 1;
  f32x4 acc[4][4] = {};

  int lrow = lane >> 3;                               // 0..7
  int lcol = (((lane & 7) ^ (lrow & 7)) & 7) * 8;     // pre-swizzled src chunk
  auto STAGE = [&](int k0) {
    #pragma unroll
    for (int it = 0; it < 4; ++it) {
      int r = w * 32 + it * 8;     // wave-uniform LDS row base
      gload_lds16(Ap + (size_t)(m0 + r + lrow) * lda + k0 + lcol, &As[r * 64]);
      int br = n0 + r + lrow; if (br > N - 1) br = N - 1;
      gload_lds16(Bp + (size_t)br * ldb + k0 + lcol, &Bs[r * 64]);
    }
  };

  int nst = K / 64;
  int rA = wr * 64 + (lane & 15);
  int rB = wc * 64 + (lane & 15);
  int sw = lane & 7, ckb = lane >> 4;
  for (int s = 0; s < nst; ++s) {
    STAGE(s * 64);
    __syncthreads();
    __builtin_amdgcn_s_setprio(1);
    #pragma unroll
    for (int ks = 0; ks < 2; ++ks) {
      int ca = (((ks * 4 + ckb) ^ sw) & 7) * 8;       // swizzled read chunk
      bf16x8 a[4], b[4];
      #pragma unroll
      for (int i = 0; i < 4; ++i) a[i] = *(const bf16x8*)(&As[(rA + i * 16) * 64 + ca]);
      #pragma unroll
      for (int i = 0; i < 4; ++i) b[i] = *(const bf16x8*)(&Bs[(rB + i * 16) * 64 + ca]);
      #pragma unroll
      for (int mi = 0; mi < 4; ++mi)
        #pragma unroll
        for (int ni = 0; ni < 4; ++ni)
          acc[mi][ni] = __builtin_amdgcn_mfma_f32_16x16x32_bf16(a[mi], b[ni], acc[mi][ni], 0, 0, 0);
    }
    __builtin_amdgcn_s_setprio(0);
    __syncthreads();
  }

  int g = lane >> 4, c = lane & 15;
  #pragma unroll
  for (int mi = 0; mi < 4; ++mi)
    #pragma unroll
    for (int ni = 0; ni < 4; ++ni) {
      int col = n0 + wc * 64 + ni * 16 + c;
      int row0 = m0 + wr * 64 + mi * 16 + g * 4;
      if (EPI == 5) {
        if (col < N) {
          float4 o; float* ov = (float*)&o;
          #pragma unroll
          for (int r = 0; r < 4; ++r) {
            float xv = acc[mi][ni][r] + bias[col];
            ov[r] = (xv > 20.f) ? xv : log1pf(__expf(xv));
          }
          *(float4*)(&CT[(size_t)col * T_TOK + row0]) = o;
        }
      }
      if (EPI == 6) {
        if (col < N) {
          #pragma unroll
          for (int r = 0; r < 4; ++r)
            C[((size_t)split * M + row0 + r) * ldc + col] = acc[mi][ni][r];
        }
      }
      if (EPI == 7) {
        if (col < DI) {
          #pragma unroll
          for (int r = 0; r < 4; ++r)
            C[(size_t)(row0 + r) * DI + col] = acc[mi][ni][r];
        } else {
          float4 o; float* ov = (float*)&o;
          #pragma unroll
          for (int r = 0; r < 4; ++r) {
            float zv = acc[mi][ni][r];
            ov[r] = zv / (1.f + __expf(-zv));
          }
          *(float4*)(&CT[(size_t)(col - DI) * T_TOK + row0]) = o;
        }
      }
    }
}

// ---------------------------------------------------------------------------
// x_proj split-K reduce: projbf [t][80] bf16 + BCt [32][t] f32
__global__ __launch_bounds__(256) void xproj_reduce_kernel(
    const float* __restrict__ part, unsigned short* __restrict__ projbf,
    float* __restrict__ BCt) {
  int idx = blockIdx.x * 256 + threadIdx.x;   // T_TOK*80
  int row = idx / 80, col = idx - row * 80;
  float v = part[idx] + part[(size_t)T_TOK * 80 + idx] +
            part[(size_t)2 * T_TOK * 80 + idx] + part[(size_t)3 * T_TOK * 80 + idx];
  projbf[idx] = f2b(v);
  if (col >= RRANK) BCt[(size_t)(col - RRANK) * T_TOK + row] = v;
}

// ---------------------------------------------------------------------------
// Logits GEMM + fused LSE partials.  128x256 tile, 8 waves (R11, unchanged).
__global__ __launch_bounds__(512) void gemm_lse_kernel(
    const unsigned short* __restrict__ A,
    const unsigned short* __restrict__ B,
    float* __restrict__ pmax, float* __restrict__ psum,
    int mtiles) {
  __shared__ __attribute__((aligned(16))) unsigned short As[128 * 64];
  __shared__ __attribute__((aligned(16))) unsigned short Bs[256 * 64];
  __shared__ float lmax[128][4];
  __shared__ float lsum[128][4];
  const int K = DM, Nv = VOCAB;
  int bid = blockIdx.x;
  int m0 = (bid % mtiles) * 128;
  int n0 = (bid / mtiles) * 256;
  int tid = threadIdx.x;
  int lane = tid & 63, w = tid >> 6;   // 8 waves
  int wr = w >> 2, wc = w & 3;         // 2 x 4; per-wave output 64x64
  f32x4 acc[4][4] = {};

  int lrow = lane >> 3;
  int lcol = (((lane & 7) ^ (lrow & 7)) & 7) * 8;   // pre-swizzled src chunk
  auto STAGE = [&](int k0) {
    #pragma unroll
    for (int it = 0; it < 2; ++it) {            // A: 8 waves x 16 rows
      int r = w * 16 + it * 8;
      gload_lds16(A + (size_t)(m0 + r + lrow) * K + k0 + lcol, &As[r * 64]);
    }
    #pragma unroll
    for (int it = 0; it < 4; ++it) {            // B: 8 waves x 32 rows
      int r = w * 32 + it * 8;
      int br = n0 + r + lrow; if (br > Nv - 1) br = Nv - 1;
      gload_lds16(B + (size_t)br * K + k0 + lcol, &Bs[r * 64]);
    }
  };

  const int nst = K / 64;   // 12
  int rA = wr * 64 + (lane & 15);
  int rB = wc * 64 + (lane & 15);
  int sw = lane & 7, ckb = lane >> 4;
  for (int s = 0; s < nst; ++s) {
    STAGE(s * 64);
    __syncthreads();
    __builtin_amdgcn_s_setprio(1);
    #pragma unroll
    for (int ks = 0; ks < 2; ++ks) {
      int ca = (((ks * 4 + ckb) ^ sw) & 7) * 8;
      bf16x8 a[4], b[4];
      #pragma unroll
      for (int i = 0; i < 4; ++i) a[i] = *(const bf16x8*)(&As[(rA + i * 16) * 64 + ca]);
      #pragma unroll
      for (int i = 0; i < 4; ++i) b[i] = *(const bf16x8*)(&Bs[(rB + i * 16) * 64 + ca]);
      #pragma unroll
      for (int mi = 0; mi < 4; ++mi)
        #pragma unroll
        for (int ni = 0; ni < 4; ++ni)
          acc[mi][ni] = __builtin_amdgcn_mfma_f32_16x16x32_bf16(a[mi], b[ni], acc[mi][ni], 0, 0, 0);
    }
    __builtin_amdgcn_s_setprio(0);
    __syncthreads();
  }

  // Row-wise (max, sum exp) over this block's 256 columns (4 wc groups).
  int g = lane >> 4, c = lane & 15;
  #pragma unroll
  for (int mi = 0; mi < 4; ++mi) {
    #pragma unroll
    for (int r = 0; r < 4; ++r) {
      float mx = -INFINITY;
      #pragma unroll
      for (int ni = 0; ni < 4; ++ni) {
        int col = n0 + wc * 64 + ni * 16 + c;
        float v = (col < Nv) ? acc[mi][ni][r] : -INFINITY;
        mx = fmaxf(mx, v);
      }
      mx = fmaxf(mx, __shfl_xor(mx, 1, 16));
      mx = fmaxf(mx, __shfl_xor(mx, 2, 16));
      mx = fmaxf(mx, __shfl_xor(mx, 4, 16));
      mx = fmaxf(mx, __shfl_xor(mx, 8, 16));
      float ssum = 0.f;
      #pragma unroll
      for (int ni = 0; ni < 4; ++ni) {
        int col = n0 + wc * 64 + ni * 16 + c;
        if (col < Nv) ssum += __expf(acc[mi][ni][r] - mx);
      }
      ssum += __shfl_xor(ssum, 1, 16);
      ssum += __shfl_xor(ssum, 2, 16);
      ssum += __shfl_xor(ssum, 4, 16);
      ssum += __shfl_xor(ssum, 8, 16);
      if (c == 0) {
        int rl = wr * 64 + mi * 16 + g * 4 + r;
        lmax[rl][wc] = mx;
        lsum[rl][wc] = ssum;
      }
    }
  }
  __syncthreads();
  if (tid < 128) {
    float m0v = lmax[tid][0], m1 = lmax[tid][1], m2 = lmax[tid][2], m3 = lmax[tid][3];
    float Mx = fmaxf(fmaxf(m0v, m1), fmaxf(m2, m3));
    float S = lsum[tid][0] * __expf(m0v - Mx) + lsum[tid][1] * __expf(m1 - Mx) +
              lsum[tid][2] * __expf(m2 - Mx) + lsum[tid][3] * __expf(m3 - Mx);
    int row = m0 + tid;
    int nb = n0 >> 8;
    pmax[(size_t)row * NTILE_V + nb] = Mx;
    psum[(size_t)row * NTILE_V + nb] = S;
  }
}

// ---------------------------------------------------------------------------
// Tiled causal depthwise conv (K=4) + silu on u only.
__global__ __launch_bounds__(256) void conv_silu_kernel(
    const float* __restrict__ ur, const float* __restrict__ cw,
    const float* __restrict__ cb,
    unsigned short* __restrict__ ucbf, float* __restrict__ ucT) {
  __shared__ float xu[67][64];
  __shared__ float ou[64][65];
  int t0 = blockIdx.x * 64;
  int ch0 = blockIdx.y * 64;
  int tid = threadIdx.x;
  int cx = tid & 63, ty = tid >> 6;           // ty 0..3
  bool seq_start = (t0 & 511) == 0;
  for (int r = ty; r < 67; r += 4) {
    int tg = t0 - 3 + r;
    float v = 0.f;
    if (r >= 3 || !seq_start) v = ur[(size_t)tg * DI + ch0 + cx];
    xu[r][cx] = v;
  }
  __syncthreads();
  int ch = ch0 + cx;
  float4 wv = *(const float4*)(cw + ch * 4);
  float bias = cb[ch];
  #pragma unroll
  for (int i = 0; i < 16; ++i) {
    int tr = ty * 16 + i;
    float a = bias + xu[tr][cx] * wv.x + xu[tr + 1][cx] * wv.y +
              xu[tr + 2][cx] * wv.z + xu[tr + 3][cx] * wv.w;
    float s = a / (1.f + __expf(-a));
    ucbf[(size_t)(t0 + tr) * DI + ch] = f2b(s);
    ou[tr][cx] = s;
  }
  __syncthreads();
  int tx = tid & 63, cy = tid >> 6;
  #pragma unroll
  for (int i = 0; i < 16; ++i) {
    int chi = cy * 16 + i;
    ucT[(size_t)(ch0 + chi) * T_TOK + t0 + tx] = ou[tx][chi];
  }
}

// ---------------------------------------------------------------------------
// Scan phase 1: per-(b,d,n,chunk) summary.
__global__ __launch_bounds__(256) void scan_sum_kernel(
    const float* __restrict__ dtT, const float* __restrict__ ucT,
    const float* __restrict__ BCt, const float* __restrict__ Alog,
    float* __restrict__ Pbuf, float* __restrict__ Fbuf) {
  int bc = blockIdx.x / 96;                 // b*8+chunk
  int idx = (blockIdx.x % 96) * 256 + threadIdx.x;
  int n = idx & 15, d = idx >> 4;
  int b = bc >> 3, chunk = bc & 7;
  float A = -__expf(Alog[d * NST + n]);
  int t0 = b * SEQL + chunk * CHL;
  const float4* dp = (const float4*)(dtT + (size_t)d * T_TOK + t0);
  const float4* up = (const float4*)(ucT + (size_t)d * T_TOK + t0);
  const float4* Bp = (const float4*)(BCt + (size_t)n * T_TOK + t0);
  float h = 0.f, sdt = 0.f;
  #pragma unroll
  for (int q = 0; q < CHL / 4; ++q) {
    float4 d4 = dp[q], u4 = up[q], B4 = Bp[q];
    float a;
    a = __expf(d4.x * A); h = fmaf(a, h, d4.x * u4.x * B4.x);
    a = __expf(d4.y * A); h = fmaf(a, h, d4.y * u4.y * B4.y);
    a = __expf(d4.z * A); h = fmaf(a, h, d4.z * u4.z * B4.z);
    a = __expf(d4.w * A); h = fmaf(a, h, d4.w * u4.w * B4.w);
    sdt += d4.x + d4.y + d4.z + d4.w;
  }
  size_t s = ((size_t)bc * DI + d) * NST + n;
  Pbuf[s] = __expf(A * sdt);
  Fbuf[s] = h;
}

// ---------------------------------------------------------------------------
// Scan phase 3 + fused gate.
__global__ __launch_bounds__(256) void scan_emit_kernel(
    const float* __restrict__ dtT, const float* __restrict__ ucT,
    const float* __restrict__ BCt, const float* __restrict__ zsT,
    const float* __restrict__ Alog, const float* __restrict__ Dpar,
    const float* __restrict__ Pbuf, const float* __restrict__ Fbuf,
    unsigned short* __restrict__ yg) {
  int bc = blockIdx.x / 96;                 // b*8+chunk
  int idx = (blockIdx.x % 96) * 256 + threadIdx.x;
  int n = idx & 15, d = idx >> 4;
  int b = bc >> 3, chunk = bc & 7;
  float A = -__expf(Alog[d * NST + n]);
  float Dpv = Dpar[d];
  float h = 0.f;
  for (int j = 0; j < chunk; ++j) {
    size_t s = (((size_t)(b * NCHUNK + j)) * DI + d) * NST + n;
    h = Fbuf[s] + Pbuf[s] * h;
  }
  int t0 = b * SEQL + chunk * CHL;
  const float4* dp = (const float4*)(dtT + (size_t)d * T_TOK + t0);
  const float4* up = (const float4*)(ucT + (size_t)d * T_TOK + t0);
  const float4* Bp = (const float4*)(BCt + (size_t)n * T_TOK + t0);
  const float4* Cp = (const float4*)(BCt + (size_t)(NST + n) * T_TOK + t0);
  const float4* zp = (const float4*)(zsT + (size_t)d * T_TOK + t0);
  unsigned short* yp = yg + (size_t)t0 * DI + d;
  #pragma unroll 4
  for (int q = 0; q < CHL / 4; ++q) {
    float4 d4 = dp[q], u4 = up[q], B4 = Bp[q], C4 = Cp[q], z4 = zp[q];
    float y0, y1, y2, y3, a, cc;
    a = __expf(d4.x * A); h = fmaf(a, h, d4.x * u4.x * B4.x); cc = h * C4.x;
    cc += __shfl_xor(cc, 1, 16); cc += __shfl_xor(cc, 2, 16);
    cc += __shfl_xor(cc, 4, 16); cc += __shfl_xor(cc, 8, 16);
    y0 = (cc + u4.x * Dpv) * z4.x;
    a = __expf(d4.y * A); h = fmaf(a, h, d4.y * u4.y * B4.y); cc = h * C4.y;
    cc += __shfl_xor(cc, 1, 16); cc += __shfl_xor(cc, 2, 16);
    cc += __shfl_xor(cc, 4, 16); cc += __shfl_xor(cc, 8, 16);
    y1 = (cc + u4.y * Dpv) * z4.y;
    a = __expf(d4.z * A); h = fmaf(a, h, d4.z * u4.z * B4.z); cc = h * C4.z;
    cc += __shfl_xor(cc, 1, 16); cc += __shfl_xor(cc, 2, 16);
    cc += __shfl_xor(cc, 4, 16); cc += __shfl_xor(cc, 8, 16);
    y2 = (cc + u4.z * Dpv) * z4.z;
    a = __expf(d4.w * A); h = fmaf(a, h, d4.w * u4.w * B4.w); cc = h * C4.w;
    cc += __shfl_xor(cc, 1, 16); cc += __shfl_xor(cc, 2, 16);
    cc += __shfl_xor(cc, 4, 16); cc += __shfl_xor(cc, 8, 16);
    y3 = (cc + u4.w * Dpv) * z4.w;
    if (n == 0) {
      yp[(size_t)(q * 4 + 0) * DI] = f2b(y0);
      yp[(size_t)(q * 4 + 1) * DI] = f2b(y1);
      yp[(size_t)(q * 4 + 2) * DI] = f2b(y2);
      yp[(size_t)(q * 4 + 3) * DI] = f2b(y3);
    }
  }
}

// ---------------------------------------------------------------------------
// Fused LSE-reduce + label-dot: per row nll*mask and mask.  Grid T_TOK/4.
__global__ __launch_bounds__(256) void lse_label_kernel(
    const float* __restrict__ pmax, const float* __restrict__ psum,
    const unsigned short* __restrict__ h, const unsigned short* __restrict__ eb,
    const int* __restrict__ qids, const int* __restrict__ qmask,
    const int* __restrict__ aids, const int* __restrict__ amask,
    float* __restrict__ nllm, float* __restrict__ mrow) {
  int row = blockIdx.x * 4 + (threadIdx.x >> 6);
  int lane = threadIdx.x & 63;
  const float* pm = pmax + (size_t)row * NTILE_V;
  const float* ps = psum + (size_t)row * NTILE_V;
  float m = -INFINITY;
  for (int j = lane; j < NTILE_V; j += 64) m = fmaxf(m, pm[j]);
  for (int o = 1; o < 64; o <<= 1) m = fmaxf(m, __shfl_xor(m, o));
  float s = 0.f;
  for (int j = lane; j < NTILE_V; j += 64) s += ps[j] * __expf(pm[j] - m);
  for (int o = 1; o < 64; o <<= 1) s += __shfl_xor(s, o);
  float lse = m + __logf(s);
  int pos = row & 511, seq = row >> 9;
  float nll = 0.f, mv = 0.f;
  if (pos != 511) {
    const int* ids = (seq < 2) ? qids : aids;
    const int* msk = (seq < 2) ? qmask : amask;
    int lbl = ids[(seq & 1) * SEQL + pos + 1];
    mv = (float)msk[(seq & 1) * SEQL + pos + 1];
    const unsigned short* hr = h + (size_t)row * DM;
    const unsigned short* er = eb + (size_t)lbl * DM;
    float dt = 0.f;
    for (int k = lane; k < DM; k += 64) dt += b2f(hr[k]) * b2f(er[k]);
    for (int o = 1; o < 64; o <<= 1) dt += __shfl_xor(dt, o);
    nll = (lse - dt) * mv;
  }
  if (lane == 0) { nllm[row] = nll; mrow[row] = mv; }
}

// ---------------------------------------------------------------------------
// Final loss reduce
__global__ __launch_bounds__(256) void loss2_kernel(
    const float* __restrict__ nllm, const float* __restrict__ mrow,
    float* __restrict__ out) {
  float nq = 0.f, dq = 0.f, na = 0.f, da = 0.f;
  for (int row = threadIdx.x; row < T_TOK; row += 256) {
    int seq = row >> 9;
    if (seq < 2) { nq += nllm[row]; dq += mrow[row]; }
    else         { na += nllm[row]; da += mrow[row]; }
  }
  for (int o = 1; o < 64; o <<= 1) {
    nq += __shfl_xor(nq, o); dq += __shfl_xor(dq, o);
    na += __shfl_xor(na, o); da += __shfl_xor(da, o);
  }
  __shared__ float red[4][4];
  int w = threadIdx.x >> 6;
  if ((threadIdx.x & 63) == 0) { red[w][0] = nq; red[w][1] = dq; red[w][2] = na; red[w][3] = da; }
  __syncthreads();
  if (threadIdx.x == 0) {
    nq = 0.f; dq = 0.f; na = 0.f; da = 0.f;
    for (int i = 0; i < 4; ++i) { nq += red[i][0]; dq += red[i][1]; na += red[i][2]; da += red[i][3]; }
    float lq = nq / fmaxf(dq, 1.f);
    float la = na / fmaxf(da, 1.f);
    out[0] = lq + la;
  }
}

// ===========================================================================
extern "C" void kernel_launch(void* const* d_in, const int* in_sizes, int n_in,
                              void* d_out, int out_size, void* d_ws, size_t ws_size,
                              hipStream_t stream) {
  const int*   qids  = (const int*)d_in[0];
  const int*   qmask = (const int*)d_in[1];
  const int*   aids  = (const int*)d_in[2];
  const int*   amask = (const int*)d_in[3];
  const float* embed = (const float*)d_in[4];
  const float* ipw   = (const float*)d_in[5];
  const float* cw    = (const float*)d_in[6];
  const float* cb    = (const float*)d_in[7];
  const float* xpw   = (const float*)d_in[8];
  const float* dtw   = (const float*)d_in[9];
  const float* dtb   = (const float*)d_in[10];
  const float* Alog  = (const float*)d_in[11];
  const float* Dp    = (const float*)d_in[12];
  const float* opw   = (const float*)d_in[13];
  const float* nw    = (const float*)d_in[14];
  const float* nfw   = (const float*)d_in[15];

  char* wp = (char*)d_ws;
  auto alloc = [&](size_t bytes) { char* p = wp; wp += (bytes + 255) & ~(size_t)255; return p; };

  float*          x      = (float*)alloc((size_t)T_TOK * DM * 4);
  unsigned short* hbf    = (unsigned short*)alloc((size_t)T_TOK * DM * 2);
  float*          ur     = (float*)alloc((size_t)T_TOK * DI * 4);
  unsigned short* ucbf   = (unsigned short*)alloc((size_t)T_TOK * DI * 2);
  unsigned short* projbf = (unsigned short*)alloc((size_t)T_TOK * 80 * 2);
  unsigned short* ygbf   = (unsigned short*)alloc((size_t)T_TOK * DI * 2);
  float*          ucT    = (float*)alloc((size_t)DI * T_TOK * 4);
  float*          zsT    = (float*)alloc((size_t)DI * T_TOK * 4);
  float*          dtT    = (float*)alloc((size_t)DI * T_TOK * 4);
  float*          BCt    = (float*)alloc((size_t)2 * NST * T_TOK * 4);
  float*          Pbuf   = (float*)alloc((size_t)4 * NCHUNK * DI * NST * 4);
  float*          Fbuf   = (float*)alloc((size_t)4 * NCHUNK * DI * NST * 4);
  float*          xpart  = (float*)alloc((size_t)4 * T_TOK * 80 * 4);
  float*          opart  = (float*)alloc((size_t)4 * T_TOK * DM * 4);
  unsigned short* ipw_t  = (unsigned short*)alloc((size_t)NLAYER * 2 * DI * DM * 2);
  unsigned short* opw_t  = (unsigned short*)alloc((size_t)NLAYER * DM * DI * 2);
  unsigned short* xpw_t  = (unsigned short*)alloc((size_t)NLAYER * 80 * DI * 2);
  unsigned short* dtw_t  = (unsigned short*)alloc((size_t)NLAYER * DI * 64 * 2);
  unsigned short* embbf  = (unsigned short*)alloc((size_t)VOCAB * DM * 2);
  float*          pmax   = (float*)alloc((size_t)T_TOK * NTILE_V * 4);
  float*          psum   = (float*)alloc((size_t)T_TOK * NTILE_V * 4);
  float*          nllm   = (float*)alloc((size_t)T_TOK * 4);
  float*          mrow   = (float*)alloc((size_t)T_TOK * 4);

  // One-time weight prep
  transpose_conv_kernel<<<dim3(96, 24, NLAYER), 256, 0, stream>>>(ipw, ipw_t, DM, 2 * DI, DM);
  transpose_conv_kernel<<<dim3(24, 48, NLAYER), 256, 0, stream>>>(opw, opw_t, DI, DM, DI);
  transpose_conv_kernel<<<dim3(3, 48, NLAYER), 256, 0, stream>>>(xpw, xpw_t, DI, 80, DI);
  transpose_conv_kernel<<<dim3(48, 2, NLAYER), 256, 0, stream>>>(dtw, dtw_t, RRANK, DI, 64);
  cvt_embed_kernel<<<2048, 256, 0, stream>>>(embed, embbf);

  // Embedding gather + layer-0 RMSNorm
  gather_rms_kernel<<<T_TOK, 256, 0, stream>>>(qids, qmask, aids, amask, embed, nw, x, hbf);

  const int mt = T_TOK / 128;  // 16 m-tiles
  for (int l = 0; l < NLAYER; ++l) {
    // in_proj (narrow, 384 blocks): u -> ur [t][DI], silu(z) -> zsT [ch][t]
    gemm_bf16_kernel<7><<<mt * (2 * DI / 128), 256, 0, stream>>>(
        hbf, DM, ipw_t + (size_t)l * 2 * DI * DM, DM, ur, zsT, DI,
        nullptr, T_TOK, 2 * DI, DM, mt);
    // conv + silu(u): ucbf [t][ch], ucT [ch][t]
    conv_silu_kernel<<<dim3(T_TOK / 64, DI / 64), 256, 0, stream>>>(
        ur, cw + (size_t)l * DI * KCONV, cb + (size_t)l * DI, ucbf, ucT);
    // x_proj split-K=4: partials (M=2048, N=80, K=384/split)
    gemm_bf16_kernel<6><<<mt * 1 * 4, 256, 0, stream>>>(
        ucbf, DI, xpw_t + (size_t)l * 80 * DI, DI, xpart, nullptr, 80,
        nullptr, T_TOK, 80, DI / 4, mt);
    xproj_reduce_kernel<<<(T_TOK * 80) / 256, 256, 0, stream>>>(xpart, projbf, BCt);
    // dtT[d][t] = softplus(proj[:, :48] @ dt_proj + b)  (K=64 zero-padded)
    gemm_bf16_kernel<5><<<mt * (DI / 128), 256, 0, stream>>>(
        projbf, 80, dtw_t + (size_t)l * DI * 64, 64, nullptr, dtT, DI,
        dtb + (size_t)l * DI, T_TOK, DI, 64, mt);
    // chunked parallel scan + fused gate
    scan_sum_kernel<<<32 * 96, 256, 0, stream>>>(
        dtT, ucT, BCt, Alog + (size_t)l * DI * NST, Pbuf, Fbuf);
    scan_emit_kernel<<<32 * 96, 256, 0, stream>>>(
        dtT, ucT, BCt, zsT, Alog + (size_t)l * DI * NST, Dp + (size_t)l * DI,
        Pbuf, Fbuf, ygbf);
    // out_proj split-K=4 partials (narrow, 384 blocks)
    gemm_bf16_kernel<6><<<mt * (DM / 128) * 4, 256, 0, stream>>>(
        ygbf, DI, opw_t + (size_t)l * DM * DI, DI, opart, nullptr, DM,
        nullptr, T_TOK, DM, DI / 4, mt);
    // x += sum(opart); h = rms(x) * w_next  (nfw after last layer)
    resid_rms_kernel<<<T_TOK, 256, 0, stream>>>(
        x, opart, (l < NLAYER - 1) ? (nw + (l + 1) * DM) : nfw, hbf);
  }

  // Fused logits/LSE + loss
  gemm_lse_kernel<<<mt * NTILE_V, 512, 0, stream>>>(hbf, embbf, pmax, psum, mt);
  lse_label_kernel<<<T_TOK / 4, 256, 0, stream>>>(
      pmax, psum, hbf, embbf, qids, qmask, aids, amask, nllm, mrow);
  loss2_kernel<<<1, 256, 0, stream>>>(nllm, mrow, (float*)d_out);
}

// Round 18
// 1111.851 us; speedup vs baseline: 1.1117x; 1.0026x over previous
//
#include <hip/hip_runtime.h>
#include <hip/hip_bf16.h>
#include <cstdint>
#include <cstddef>

// Problem constants
#define T_TOK   2048   // 4 sequences (2 question + 2 answer) x 512
#define DM      768
#define DI      1536
#define NST     16
#define RRANK   48
#define KCONV   4
#define VOCAB   50280
#define NLAYER  4
#define SEQL    512
#define NTILE_V 197    // ceil(50280/256)
#define NCHUNK  8      // time chunks per sequence
#define CHL     64     // chunk length

typedef __bf16 bf16x8 __attribute__((ext_vector_type(8)));
typedef float  f32x4  __attribute__((ext_vector_type(4)));

__device__ inline unsigned short f2b(float f) {
  union { float f; unsigned u; } v; v.f = f;
  unsigned r = v.u + 0x7FFFu + ((v.u >> 16) & 1u);   // RNE
  return (unsigned short)(r >> 16);
}
__device__ inline float b2f(unsigned short h) {
  union { unsigned u; float f; } v; v.u = ((unsigned)h) << 16;
  return v.f;
}

// global -> LDS direct 16B async copy. LDS dest is wave-uniform base; HW
// scatters lane i to base + i*16.
__device__ inline void gload_lds16(const unsigned short* g, unsigned short* l) {
  __builtin_amdgcn_global_load_lds(
      (const __attribute__((address_space(1))) void*)g,
      (__attribute__((address_space(3))) void*)l, 16, 0, 0);
}

// ---------------------------------------------------------------------------
// Transpose-convert: src f32 [R][C] -> dst bf16 [C][Rpad] (zero pad r>=R).
__global__ __launch_bounds__(256) void transpose_conv_kernel(
    const float* __restrict__ src, unsigned short* __restrict__ dst,
    int R, int C, int Rpad) {
  __shared__ float tile[32][33];
  const float* s = src + (size_t)blockIdx.z * R * C;
  unsigned short* d = dst + (size_t)blockIdx.z * C * Rpad;
  int c0 = blockIdx.x * 32, r0 = blockIdx.y * 32;
  int tx = threadIdx.x & 31, ty = threadIdx.x >> 5; // ty 0..7
  #pragma unroll
  for (int i = 0; i < 32; i += 8) {
    int r = r0 + ty + i, c = c0 + tx;
    tile[ty + i][tx] = (r < R && c < C) ? s[(size_t)r * C + c] : 0.f;
  }
  __syncthreads();
  #pragma unroll
  for (int i = 0; i < 32; i += 8) {
    int c = c0 + ty + i, r = r0 + tx;
    if (c < C && r < Rpad) d[(size_t)c * Rpad + r] = f2b(tile[tx][ty + i]);
  }
}

// ---------------------------------------------------------------------------
// embed f32 -> bf16 (grid-stride)
__global__ __launch_bounds__(256) void cvt_embed_kernel(
    const float* __restrict__ e, unsigned short* __restrict__ eb) {
  const int n4 = VOCAB * DM / 4;
  for (int i = blockIdx.x * 256 + threadIdx.x; i < n4; i += gridDim.x * 256) {
    float4 f = *(const float4*)(e + (size_t)i * 4);
    union { unsigned long long u; unsigned short h[4]; } pk;
    pk.h[0] = f2b(f.x); pk.h[1] = f2b(f.y); pk.h[2] = f2b(f.z); pk.h[3] = f2b(f.w);
    *(unsigned long long*)(eb + (size_t)i * 4) = pk.u;
  }
}

// ---------------------------------------------------------------------------
// Fused embedding gather + layer-0 RMSNorm.  Grid T_TOK blocks.
__global__ __launch_bounds__(256) void gather_rms_kernel(
    const int* __restrict__ qids, const int* __restrict__ qmask,
    const int* __restrict__ aids, const int* __restrict__ amask,
    const float* __restrict__ embed, const float* __restrict__ w,
    float* __restrict__ x, unsigned short* __restrict__ h) {
  int t = blockIdx.x;
  int seq = t >> 9, pos = t & 511;
  const int* ids = (seq < 2) ? qids : aids;
  const int* msk = (seq < 2) ? qmask : amask;
  int s2 = seq & 1;
  int id = ids[s2 * SEQL + pos];
  float m = (float)msk[s2 * SEQL + pos];
  const float* er = embed + (size_t)id * DM;
  float v[3], ss = 0.f;
  #pragma unroll
  for (int j = 0; j < 3; ++j) {
    int d = threadIdx.x + j * 256;
    float vv = er[d] * m;
    x[(size_t)t * DM + d] = vv;
    v[j] = vv; ss += vv * vv;
  }
  for (int o = 1; o < 64; o <<= 1) ss += __shfl_xor(ss, o);
  __shared__ float wsum[4];
  if ((threadIdx.x & 63) == 0) wsum[threadIdx.x >> 6] = ss;
  __syncthreads();
  ss = wsum[0] + wsum[1] + wsum[2] + wsum[3];
  float sc = rsqrtf(ss / (float)DM + 1e-5f);
  #pragma unroll
  for (int j = 0; j < 3; ++j) {
    int d = threadIdx.x + j * 256;
    h[(size_t)t * DM + d] = f2b(v[j] * sc * w[d]);
  }
}

// ---------------------------------------------------------------------------
// Fused: x += sum(out_proj partials); h = rms(x)*w  (next layer / final norm)
__global__ __launch_bounds__(256) void resid_rms_kernel(
    float* __restrict__ x, const float* __restrict__ part,
    const float* __restrict__ w, unsigned short* __restrict__ h) {
  int t = blockIdx.x;
  float v[3];
  float ss = 0.f;
  #pragma unroll
  for (int j = 0; j < 3; ++j) {
    int d = threadIdx.x + j * 256;
    size_t o = (size_t)t * DM + d;
    float xv = x[o] + part[o] + part[(size_t)T_TOK * DM + o] +
               part[(size_t)2 * T_TOK * DM + o] + part[(size_t)3 * T_TOK * DM + o];
    x[o] = xv; v[j] = xv; ss += xv * xv;
  }
  for (int o = 1; o < 64; o <<= 1) ss += __shfl_xor(ss, o);
  __shared__ float wsum[4];
  if ((threadIdx.x & 63) == 0) wsum[threadIdx.x >> 6] = ss;
  __syncthreads();
  ss = wsum[0] + wsum[1] + wsum[2] + wsum[3];
  float sc = rsqrtf(ss / (float)DM + 1e-5f);
  #pragma unroll
  for (int j = 0; j < 3; ++j) {
    int d = threadIdx.x + j * 256;
    h[(size_t)t * DM + d] = f2b(v[j] * sc * w[d]);
  }
}

// ---------------------------------------------------------------------------
// Narrow GEMM: 128x128 tile, 4 waves, single-buffered + XOR-swizzle (m97).
// EPI 5 = dt: softplus(acc+bias[col]) -> CT[col*T_TOK+row] float4
// EPI 6 = split-K partial: C[(split*M+row)*ldc+col]
// EPI 7 = in_proj: col<DI -> ((ushort*)C)[row*DI+col]=bf16(u); col>=DI ->
//         silu -> CT[(col-DI)*T_TOK+row] transposed float4
template <int EPI>
__global__ __launch_bounds__(256) void gemm_bf16_kernel(
    const unsigned short* __restrict__ A, int lda,
    const unsigned short* __restrict__ B, int ldb,
    float* __restrict__ C, float* __restrict__ CT, int ldc,
    const float* __restrict__ bias,
    int M, int N, int K, int mtiles) {
  __shared__ __attribute__((aligned(16))) unsigned short As[128 * 64];
  __shared__ __attribute__((aligned(16))) unsigned short Bs[128 * 64];
  int bid = blockIdx.x;
  int m0 = (bid % mtiles) * 128;
  int rest = bid / mtiles;
  int n0, split = 0;
  int ntil = (N + 127) >> 7;
  if (EPI == 6) { split = rest / ntil; n0 = (rest % ntil) * 128; }
  else n0 = rest * 128;
  const unsigned short* Ap = (EPI == 6) ? A + (size_t)split * K : A;
  const unsigned short* Bp = (EPI == 6) ? B + (size_t)split * K : B;
  int tid = threadIdx.x;
  int lane = tid & 63, w = tid >> 6;
  int wr = w >> 1, wc = w & 1;
  f32x4 acc[4][4] = {};

  int lrow = lane >> 3;                               // 0..7
  int lcol = (((lane & 7) ^ (lrow & 7)) & 7) * 8;     // pre-swizzled src chunk
  auto STAGE = [&](int k0) {
    #pragma unroll
    for (int it = 0; it < 4; ++it) {
      int r = w * 32 + it * 8;     // wave-uniform LDS row base
      gload_lds16(Ap + (size_t)(m0 + r + lrow) * lda + k0 + lcol, &As[r * 64]);
      int br = n0 + r + lrow; if (br > N - 1) br = N - 1;
      gload_lds16(Bp + (size_t)br * ldb + k0 + lcol, &Bs[r * 64]);
    }
  };

  int nst = K / 64;
  int rA = wr * 64 + (lane & 15);
  int rB = wc * 64 + (lane & 15);
  int sw = lane & 7, ckb = lane >> 4;
  for (int s = 0; s < nst; ++s) {
    STAGE(s * 64);
    __syncthreads();
    __builtin_amdgcn_s_setprio(1);
    #pragma unroll
    for (int ks = 0; ks < 2; ++ks) {
      int ca = (((ks * 4 + ckb) ^ sw) & 7) * 8;       // swizzled read chunk
      bf16x8 a[4], b[4];
      #pragma unroll
      for (int i = 0; i < 4; ++i) a[i] = *(const bf16x8*)(&As[(rA + i * 16) * 64 + ca]);
      #pragma unroll
      for (int i = 0; i < 4; ++i) b[i] = *(const bf16x8*)(&Bs[(rB + i * 16) * 64 + ca]);
      #pragma unroll
      for (int mi = 0; mi < 4; ++mi)
        #pragma unroll
        for (int ni = 0; ni < 4; ++ni)
          acc[mi][ni] = __builtin_amdgcn_mfma_f32_16x16x32_bf16(a[mi], b[ni], acc[mi][ni], 0, 0, 0);
    }
    __builtin_amdgcn_s_setprio(0);
    __syncthreads();
  }

  int g = lane >> 4, c = lane & 15;
  #pragma unroll
  for (int mi = 0; mi < 4; ++mi)
    #pragma unroll
    for (int ni = 0; ni < 4; ++ni) {
      int col = n0 + wc * 64 + ni * 16 + c;
      int row0 = m0 + wr * 64 + mi * 16 + g * 4;
      if (EPI == 5) {
        if (col < N) {
          float4 o; float* ov = (float*)&o;
          #pragma unroll
          for (int r = 0; r < 4; ++r) {
            float xv = acc[mi][ni][r] + bias[col];
            ov[r] = (xv > 20.f) ? xv : log1pf(__expf(xv));
          }
          *(float4*)(&CT[(size_t)col * T_TOK + row0]) = o;
        }
      }
      if (EPI == 6) {
        if (col < N) {
          #pragma unroll
          for (int r = 0; r < 4; ++r)
            C[((size_t)split * M + row0 + r) * ldc + col] = acc[mi][ni][r];
        }
      }
      if (EPI == 7) {
        if (col < DI) {
          unsigned short* ub = (unsigned short*)C;
          #pragma unroll
          for (int r = 0; r < 4; ++r)
            ub[(size_t)(row0 + r) * DI + col] = f2b(acc[mi][ni][r]);
        } else {
          float4 o; float* ov = (float*)&o;
          #pragma unroll
          for (int r = 0; r < 4; ++r) {
            float zv = acc[mi][ni][r];
            ov[r] = zv / (1.f + __expf(-zv));
          }
          *(float4*)(&CT[(size_t)(col - DI) * T_TOK + row0]) = o;
        }
      }
    }
}

// ---------------------------------------------------------------------------
// x_proj split-K reduce: projbf [t][80] bf16 + BCt [32][t] f32
__global__ __launch_bounds__(256) void xproj_reduce_kernel(
    const float* __restrict__ part, unsigned short* __restrict__ projbf,
    float* __restrict__ BCt) {
  int idx = blockIdx.x * 256 + threadIdx.x;   // T_TOK*80
  int row = idx / 80, col = idx - row * 80;
  float v = part[idx] + part[(size_t)T_TOK * 80 + idx] +
            part[(size_t)2 * T_TOK * 80 + idx] + part[(size_t)3 * T_TOK * 80 + idx];
  projbf[idx] = f2b(v);
  if (col >= RRANK) BCt[(size_t)(col - RRANK) * T_TOK + row] = v;
}

// ---------------------------------------------------------------------------
// Logits GEMM + fused LSE partials.  128x256 tile, 8 waves (R11, unchanged).
__global__ __launch_bounds__(512) void gemm_lse_kernel(
    const unsigned short* __restrict__ A,
    const unsigned short* __restrict__ B,
    float* __restrict__ pmax, float* __restrict__ psum,
    int mtiles) {
  __shared__ __attribute__((aligned(16))) unsigned short As[128 * 64];
  __shared__ __attribute__((aligned(16))) unsigned short Bs[256 * 64];
  __shared__ float lmax[128][4];
  __shared__ float lsum[128][4];
  const int K = DM, Nv = VOCAB;
  int bid = blockIdx.x;
  int m0 = (bid % mtiles) * 128;
  int n0 = (bid / mtiles) * 256;
  int tid = threadIdx.x;
  int lane = tid & 63, w = tid >> 6;   // 8 waves
  int wr = w >> 2, wc = w & 3;         // 2 x 4; per-wave output 64x64
  f32x4 acc[4][4] = {};

  int lrow = lane >> 3;
  int lcol = (((lane & 7) ^ (lrow & 7)) & 7) * 8;   // pre-swizzled src chunk
  auto STAGE = [&](int k0) {
    #pragma unroll
    for (int it = 0; it < 2; ++it) {            // A: 8 waves x 16 rows
      int r = w * 16 + it * 8;
      gload_lds16(A + (size_t)(m0 + r + lrow) * K + k0 + lcol, &As[r * 64]);
    }
    #pragma unroll
    for (int it = 0; it < 4; ++it) {            // B: 8 waves x 32 rows
      int r = w * 32 + it * 8;
      int br = n0 + r + lrow; if (br > Nv - 1) br = Nv - 1;
      gload_lds16(B + (size_t)br * K + k0 + lcol, &Bs[r * 64]);
    }
  };

  const int nst = K / 64;   // 12
  int rA = wr * 64 + (lane & 15);
  int rB = wc * 64 + (lane & 15);
  int sw = lane & 7, ckb = lane >> 4;
  for (int s = 0; s < nst; ++s) {
    STAGE(s * 64);
    __syncthreads();
    __builtin_amdgcn_s_setprio(1);
    #pragma unroll
    for (int ks = 0; ks < 2; ++ks) {
      int ca = (((ks * 4 + ckb) ^ sw) & 7) * 8;
      bf16x8 a[4], b[4];
      #pragma unroll
      for (int i = 0; i < 4; ++i) a[i] = *(const bf16x8*)(&As[(rA + i * 16) * 64 + ca]);
      #pragma unroll
      for (int i = 0; i < 4; ++i) b[i] = *(const bf16x8*)(&Bs[(rB + i * 16) * 64 + ca]);
      #pragma unroll
      for (int mi = 0; mi < 4; ++mi)
        #pragma unroll
        for (int ni = 0; ni < 4; ++ni)
          acc[mi][ni] = __builtin_amdgcn_mfma_f32_16x16x32_bf16(a[mi], b[ni], acc[mi][ni], 0, 0, 0);
    }
    __builtin_amdgcn_s_setprio(0);
    __syncthreads();
  }

  // Row-wise (max, sum exp) over this block's 256 columns (4 wc groups).
  int g = lane >> 4, c = lane & 15;
  #pragma unroll
  for (int mi = 0; mi < 4; ++mi) {
    #pragma unroll
    for (int r = 0; r < 4; ++r) {
      float mx = -INFINITY;
      #pragma unroll
      for (int ni = 0; ni < 4; ++ni) {
        int col = n0 + wc * 64 + ni * 16 + c;
        float v = (col < Nv) ? acc[mi][ni][r] : -INFINITY;
        mx = fmaxf(mx, v);
      }
      mx = fmaxf(mx, __shfl_xor(mx, 1, 16));
      mx = fmaxf(mx, __shfl_xor(mx, 2, 16));
      mx = fmaxf(mx, __shfl_xor(mx, 4, 16));
      mx = fmaxf(mx, __shfl_xor(mx, 8, 16));
      float ssum = 0.f;
      #pragma unroll
      for (int ni = 0; ni < 4; ++ni) {
        int col = n0 + wc * 64 + ni * 16 + c;
        if (col < Nv) ssum += __expf(acc[mi][ni][r] - mx);
      }
      ssum += __shfl_xor(ssum, 1, 16);
      ssum += __shfl_xor(ssum, 2, 16);
      ssum += __shfl_xor(ssum, 4, 16);
      ssum += __shfl_xor(ssum, 8, 16);
      if (c == 0) {
        int rl = wr * 64 + mi * 16 + g * 4 + r;
        lmax[rl][wc] = mx;
        lsum[rl][wc] = ssum;
      }
    }
  }
  __syncthreads();
  if (tid < 128) {
    float m0v = lmax[tid][0], m1 = lmax[tid][1], m2 = lmax[tid][2], m3 = lmax[tid][3];
    float Mx = fmaxf(fmaxf(m0v, m1), fmaxf(m2, m3));
    float S = lsum[tid][0] * __expf(m0v - Mx) + lsum[tid][1] * __expf(m1 - Mx) +
              lsum[tid][2] * __expf(m2 - Mx) + lsum[tid][3] * __expf(m3 - Mx);
    int row = m0 + tid;
    int nb = n0 >> 8;
    pmax[(size_t)row * NTILE_V + nb] = Mx;
    psum[(size_t)row * NTILE_V + nb] = S;
  }
}

// ---------------------------------------------------------------------------
// Tiled causal depthwise conv (K=4) + silu on u only (bf16 input).
__global__ __launch_bounds__(256) void conv_silu_kernel(
    const unsigned short* __restrict__ ur, const float* __restrict__ cw,
    const float* __restrict__ cb,
    unsigned short* __restrict__ ucbf, float* __restrict__ ucT) {
  __shared__ float xu[67][64];
  __shared__ float ou[64][65];
  int t0 = blockIdx.x * 64;
  int ch0 = blockIdx.y * 64;
  int tid = threadIdx.x;
  int cx = tid & 63, ty = tid >> 6;           // ty 0..3
  bool seq_start = (t0 & 511) == 0;
  for (int r = ty; r < 67; r += 4) {
    int tg = t0 - 3 + r;
    float v = 0.f;
    if (r >= 3 || !seq_start) v = b2f(ur[(size_t)tg * DI + ch0 + cx]);
    xu[r][cx] = v;
  }
  __syncthreads();
  int ch = ch0 + cx;
  float4 wv = *(const float4*)(cw + ch * 4);
  float bias = cb[ch];
  #pragma unroll
  for (int i = 0; i < 16; ++i) {
    int tr = ty * 16 + i;
    float a = bias + xu[tr][cx] * wv.x + xu[tr + 1][cx] * wv.y +
              xu[tr + 2][cx] * wv.z + xu[tr + 3][cx] * wv.w;
    float s = a / (1.f + __expf(-a));
    ucbf[(size_t)(t0 + tr) * DI + ch] = f2b(s);
    ou[tr][cx] = s;
  }
  __syncthreads();
  int tx = tid & 63, cy = tid >> 6;
  #pragma unroll
  for (int i = 0; i < 16; ++i) {
    int chi = cy * 16 + i;
    ucT[(size_t)(ch0 + chi) * T_TOK + t0 + tx] = ou[tx][chi];
  }
}

// ---------------------------------------------------------------------------
// Scan phase 1: per-(b,d,n,chunk) summary.
__global__ __launch_bounds__(256) void scan_sum_kernel(
    const float* __restrict__ dtT, const float* __restrict__ ucT,
    const float* __restrict__ BCt, const float* __restrict__ Alog,
    float* __restrict__ Pbuf, float* __restrict__ Fbuf) {
  int bc = blockIdx.x / 96;                 // b*8+chunk
  int idx = (blockIdx.x % 96) * 256 + threadIdx.x;
  int n = idx & 15, d = idx >> 4;
  int b = bc >> 3, chunk = bc & 7;
  float A = -__expf(Alog[d * NST + n]);
  int t0 = b * SEQL + chunk * CHL;
  const float4* dp = (const float4*)(dtT + (size_t)d * T_TOK + t0);
  const float4* up = (const float4*)(ucT + (size_t)d * T_TOK + t0);
  const float4* Bp = (const float4*)(BCt + (size_t)n * T_TOK + t0);
  float h = 0.f, sdt = 0.f;
  #pragma unroll
  for (int q = 0; q < CHL / 4; ++q) {
    float4 d4 = dp[q], u4 = up[q], B4 = Bp[q];
    float a;
    a = __expf(d4.x * A); h = fmaf(a, h, d4.x * u4.x * B4.x);
    a = __expf(d4.y * A); h = fmaf(a, h, d4.y * u4.y * B4.y);
    a = __expf(d4.z * A); h = fmaf(a, h, d4.z * u4.z * B4.z);
    a = __expf(d4.w * A); h = fmaf(a, h, d4.w * u4.w * B4.w);
    sdt += d4.x + d4.y + d4.z + d4.w;
  }
  size_t s = ((size_t)bc * DI + d) * NST + n;
  Pbuf[s] = __expf(A * sdt);
  Fbuf[s] = h;
}

// ---------------------------------------------------------------------------
// Scan phase 3 + fused gate.
__global__ __launch_bounds__(256) void scan_emit_kernel(
    const float* __restrict__ dtT, const float* __restrict__ ucT,
    const float* __restrict__ BCt, const float* __restrict__ zsT,
    const float* __restrict__ Alog, const float* __restrict__ Dpar,
    const float* __restrict__ Pbuf, const float* __restrict__ Fbuf,
    unsigned short* __restrict__ yg) {
  int bc = blockIdx.x / 96;                 // b*8+chunk
  int idx = (blockIdx.x % 96) * 256 + threadIdx.x;
  int n = idx & 15, d = idx >> 4;
  int b = bc >> 3, chunk = bc & 7;
  float A = -__expf(Alog[d * NST + n]);
  float Dpv = Dpar[d];
  float h = 0.f;
  for (int j = 0; j < chunk; ++j) {
    size_t s = (((size_t)(b * NCHUNK + j)) * DI + d) * NST + n;
    h = Fbuf[s] + Pbuf[s] * h;
  }
  int t0 = b * SEQL + chunk * CHL;
  const float4* dp = (const float4*)(dtT + (size_t)d * T_TOK + t0);
  const float4* up = (const float4*)(ucT + (size_t)d * T_TOK + t0);
  const float4* Bp = (const float4*)(BCt + (size_t)n * T_TOK + t0);
  const float4* Cp = (const float4*)(BCt + (size_t)(NST + n) * T_TOK + t0);
  const float4* zp = (const float4*)(zsT + (size_t)d * T_TOK + t0);
  unsigned short* yp = yg + (size_t)t0 * DI + d;
  #pragma unroll 4
  for (int q = 0; q < CHL / 4; ++q) {
    float4 d4 = dp[q], u4 = up[q], B4 = Bp[q], C4 = Cp[q], z4 = zp[q];
    float y0, y1, y2, y3, a, cc;
    a = __expf(d4.x * A); h = fmaf(a, h, d4.x * u4.x * B4.x); cc = h * C4.x;
    cc += __shfl_xor(cc, 1, 16); cc += __shfl_xor(cc, 2, 16);
    cc += __shfl_xor(cc, 4, 16); cc += __shfl_xor(cc, 8, 16);
    y0 = (cc + u4.x * Dpv) * z4.x;
    a = __expf(d4.y * A); h = fmaf(a, h, d4.y * u4.y * B4.y); cc = h * C4.y;
    cc += __shfl_xor(cc, 1, 16); cc += __shfl_xor(cc, 2, 16);
    cc += __shfl_xor(cc, 4, 16); cc += __shfl_xor(cc, 8, 16);
    y1 = (cc + u4.y * Dpv) * z4.y;
    a = __expf(d4.z * A); h = fmaf(a, h, d4.z * u4.z * B4.z); cc = h * C4.z;
    cc += __shfl_xor(cc, 1, 16); cc += __shfl_xor(cc, 2, 16);
    cc += __shfl_xor(cc, 4, 16); cc += __shfl_xor(cc, 8, 16);
    y2 = (cc + u4.z * Dpv) * z4.z;
    a = __expf(d4.w * A); h = fmaf(a, h, d4.w * u4.w * B4.w); cc = h * C4.w;
    cc += __shfl_xor(cc, 1, 16); cc += __shfl_xor(cc, 2, 16);
    cc += __shfl_xor(cc, 4, 16); cc += __shfl_xor(cc, 8, 16);
    y3 = (cc + u4.w * Dpv) * z4.w;
    if (n == 0) {
      yp[(size_t)(q * 4 + 0) * DI] = f2b(y0);
      yp[(size_t)(q * 4 + 1) * DI] = f2b(y1);
      yp[(size_t)(q * 4 + 2) * DI] = f2b(y2);
      yp[(size_t)(q * 4 + 3) * DI] = f2b(y3);
    }
  }
}

// ---------------------------------------------------------------------------
// Fused LSE-reduce + label-dot: per row nll*mask and mask.  Grid T_TOK/4.
__global__ __launch_bounds__(256) void lse_label_kernel(
    const float* __restrict__ pmax, const float* __restrict__ psum,
    const unsigned short* __restrict__ h, const unsigned short* __restrict__ eb,
    const int* __restrict__ qids, const int* __restrict__ qmask,
    const int* __restrict__ aids, const int* __restrict__ amask,
    float* __restrict__ nllm, float* __restrict__ mrow) {
  int row = blockIdx.x * 4 + (threadIdx.x >> 6);
  int lane = threadIdx.x & 63;
  const float* pm = pmax + (size_t)row * NTILE_V;
  const float* ps = psum + (size_t)row * NTILE_V;
  float m = -INFINITY;
  for (int j = lane; j < NTILE_V; j += 64) m = fmaxf(m, pm[j]);
  for (int o = 1; o < 64; o <<= 1) m = fmaxf(m, __shfl_xor(m, o));
  float s = 0.f;
  for (int j = lane; j < NTILE_V; j += 64) s += ps[j] * __expf(pm[j] - m);
  for (int o = 1; o < 64; o <<= 1) s += __shfl_xor(s, o);
  float lse = m + __logf(s);
  int pos = row & 511, seq = row >> 9;
  float nll = 0.f, mv = 0.f;
  if (pos != 511) {
    const int* ids = (seq < 2) ? qids : aids;
    const int* msk = (seq < 2) ? qmask : amask;
    int lbl = ids[(seq & 1) * SEQL + pos + 1];
    mv = (float)msk[(seq & 1) * SEQL + pos + 1];
    const unsigned short* hr = h + (size_t)row * DM;
    const unsigned short* er = eb + (size_t)lbl * DM;
    float dt = 0.f;
    for (int k = lane; k < DM; k += 64) dt += b2f(hr[k]) * b2f(er[k]);
    for (int o = 1; o < 64; o <<= 1) dt += __shfl_xor(dt, o);
    nll = (lse - dt) * mv;
  }
  if (lane == 0) { nllm[row] = nll; mrow[row] = mv; }
}

// ---------------------------------------------------------------------------
// Final loss reduce
__global__ __launch_bounds__(256) void loss2_kernel(
    const float* __restrict__ nllm, const float* __restrict__ mrow,
    float* __restrict__ out) {
  float nq = 0.f, dq = 0.f, na = 0.f, da = 0.f;
  for (int row = threadIdx.x; row < T_TOK; row += 256) {
    int seq = row >> 9;
    if (seq < 2) { nq += nllm[row]; dq += mrow[row]; }
    else         { na += nllm[row]; da += mrow[row]; }
  }
  for (int o = 1; o < 64; o <<= 1) {
    nq += __shfl_xor(nq, o); dq += __shfl_xor(dq, o);
    na += __shfl_xor(na, o); da += __shfl_xor(da, o);
  }
  __shared__ float red[4][4];
  int w = threadIdx.x >> 6;
  if ((threadIdx.x & 63) == 0) { red[w][0] = nq; red[w][1] = dq; red[w][2] = na; red[w][3] = da; }
  __syncthreads();
  if (threadIdx.x == 0) {
    nq = 0.f; dq = 0.f; na = 0.f; da = 0.f;
    for (int i = 0; i < 4; ++i) { nq += red[i][0]; dq += red[i][1]; na += red[i][2]; da += red[i][3]; }
    float lq = nq / fmaxf(dq, 1.f);
    float la = na / fmaxf(da, 1.f);
    out[0] = lq + la;
  }
}

// ===========================================================================
extern "C" void kernel_launch(void* const* d_in, const int* in_sizes, int n_in,
                              void* d_out, int out_size, void* d_ws, size_t ws_size,
                              hipStream_t stream) {
  const int*   qids  = (const int*)d_in[0];
  const int*   qmask = (const int*)d_in[1];
  const int*   aids  = (const int*)d_in[2];
  const int*   amask = (const int*)d_in[3];
  const float* embed = (const float*)d_in[4];
  const float* ipw   = (const float*)d_in[5];
  const float* cw    = (const float*)d_in[6];
  const float* cb    = (const float*)d_in[7];
  const float* xpw   = (const float*)d_in[8];
  const float* dtw   = (const float*)d_in[9];
  const float* dtb   = (const float*)d_in[10];
  const float* Alog  = (const float*)d_in[11];
  const float* Dp    = (const float*)d_in[12];
  const float* opw   = (const float*)d_in[13];
  const float* nw    = (const float*)d_in[14];
  const float* nfw   = (const float*)d_in[15];

  char* wp = (char*)d_ws;
  auto alloc = [&](size_t bytes) { char* p = wp; wp += (bytes + 255) & ~(size_t)255; return p; };

  float*          x      = (float*)alloc((size_t)T_TOK * DM * 4);
  unsigned short* hbf    = (unsigned short*)alloc((size_t)T_TOK * DM * 2);
  unsigned short* ur     = (unsigned short*)alloc((size_t)T_TOK * DI * 2);
  unsigned short* ucbf   = (unsigned short*)alloc((size_t)T_TOK * DI * 2);
  unsigned short* projbf = (unsigned short*)alloc((size_t)T_TOK * 80 * 2);
  unsigned short* ygbf   = (unsigned short*)alloc((size_t)T_TOK * DI * 2);
  float*          ucT    = (float*)alloc((size_t)DI * T_TOK * 4);
  float*          zsT    = (float*)alloc((size_t)DI * T_TOK * 4);
  float*          dtT    = (float*)alloc((size_t)DI * T_TOK * 4);
  float*          BCt    = (float*)alloc((size_t)2 * NST * T_TOK * 4);
  float*          Pbuf   = (float*)alloc((size_t)4 * NCHUNK * DI * NST * 4);
  float*          Fbuf   = (float*)alloc((size_t)4 * NCHUNK * DI * NST * 4);
  float*          xpart  = (float*)alloc((size_t)4 * T_TOK * 80 * 4);
  float*          opart  = (float*)alloc((size_t)4 * T_TOK * DM * 4);
  unsigned short* ipw_t  = (unsigned short*)alloc((size_t)NLAYER * 2 * DI * DM * 2);
  unsigned short* opw_t  = (unsigned short*)alloc((size_t)NLAYER * DM * DI * 2);
  unsigned short* xpw_t  = (unsigned short*)alloc((size_t)NLAYER * 80 * DI * 2);
  unsigned short* dtw_t  = (unsigned short*)alloc((size_t)NLAYER * DI * 64 * 2);
  unsigned short* embbf  = (unsigned short*)alloc((size_t)VOCAB * DM * 2);
  float*          pmax   = (float*)alloc((size_t)T_TOK * NTILE_V * 4);
  float*          psum   = (float*)alloc((size_t)T_TOK * NTILE_V * 4);
  float*          nllm   = (float*)alloc((size_t)T_TOK * 4);
  float*          mrow   = (float*)alloc((size_t)T_TOK * 4);

  // One-time weight prep
  transpose_conv_kernel<<<dim3(96, 24, NLAYER), 256, 0, stream>>>(ipw, ipw_t, DM, 2 * DI, DM);
  transpose_conv_kernel<<<dim3(24, 48, NLAYER), 256, 0, stream>>>(opw, opw_t, DI, DM, DI);
  transpose_conv_kernel<<<dim3(3, 48, NLAYER), 256, 0, stream>>>(xpw, xpw_t, DI, 80, DI);
  transpose_conv_kernel<<<dim3(48, 2, NLAYER), 256, 0, stream>>>(dtw, dtw_t, RRANK, DI, 64);
  cvt_embed_kernel<<<2048, 256, 0, stream>>>(embed, embbf);

  // Embedding gather + layer-0 RMSNorm
  gather_rms_kernel<<<T_TOK, 256, 0, stream>>>(qids, qmask, aids, amask, embed, nw, x, hbf);

  const int mt = T_TOK / 128;  // 16 m-tiles
  for (int l = 0; l < NLAYER; ++l) {
    // in_proj (narrow, 384 blocks): u -> ur bf16 [t][DI], silu(z) -> zsT [ch][t]
    gemm_bf16_kernel<7><<<mt * (2 * DI / 128), 256, 0, stream>>>(
        hbf, DM, ipw_t + (size_t)l * 2 * DI * DM, DM, (float*)ur, zsT, DI,
        nullptr, T_TOK, 2 * DI, DM, mt);
    // conv + silu(u): ucbf [t][ch], ucT [ch][t]
    conv_silu_kernel<<<dim3(T_TOK / 64, DI / 64), 256, 0, stream>>>(
        ur, cw + (size_t)l * DI * KCONV, cb + (size_t)l * DI, ucbf, ucT);
    // x_proj split-K=4: partials (M=2048, N=80, K=384/split)
    gemm_bf16_kernel<6><<<mt * 1 * 4, 256, 0, stream>>>(
        ucbf, DI, xpw_t + (size_t)l * 80 * DI, DI, xpart, nullptr, 80,
        nullptr, T_TOK, 80, DI / 4, mt);
    xproj_reduce_kernel<<<(T_TOK * 80) / 256, 256, 0, stream>>>(xpart, projbf, BCt);
    // dtT[d][t] = softplus(proj[:, :48] @ dt_proj + b)  (K=64 zero-padded)
    gemm_bf16_kernel<5><<<mt * (DI / 128), 256, 0, stream>>>(
        projbf, 80, dtw_t + (size_t)l * DI * 64, 64, nullptr, dtT, DI,
        dtb + (size_t)l * DI, T_TOK, DI, 64, mt);
    // chunked parallel scan + fused gate
    scan_sum_kernel<<<32 * 96, 256, 0, stream>>>(
        dtT, ucT, BCt, Alog + (size_t)l * DI * NST, Pbuf, Fbuf);
    scan_emit_kernel<<<32 * 96, 256, 0, stream>>>(
        dtT, ucT, BCt, zsT, Alog + (size_t)l * DI * NST, Dp + (size_t)l * DI,
        Pbuf, Fbuf, ygbf);
    // out_proj split-K=4 partials (narrow, 384 blocks)
    gemm_bf16_kernel<6><<<mt * (DM / 128) * 4, 256, 0, stream>>>(
        ygbf, DI, opw_t + (size_t)l * DM * DI, DI, opart, nullptr, DM,
        nullptr, T_TOK, DM, DI / 4, mt);
    // x += sum(opart); h = rms(x) * w_next  (nfw after last layer)
    resid_rms_kernel<<<T_TOK, 256, 0, stream>>>(
        x, opart, (l < NLAYER - 1) ? (nw + (l + 1) * DM) : nfw, hbf);
  }

  // Fused logits/LSE + loss
  gemm_lse_kernel<<<mt * NTILE_V, 512, 0, stream>>>(hbf, embbf, pmax, psum, mt);
  lse_label_kernel<<<T_TOK / 4, 256, 0, stream>>>(
      pmax, psum, hbf, embbf, qids, qmask, aids, amask, nllm, mrow);
  loss2_kernel<<<1, 256, 0, stream>>>(nllm, mrow, (float*)d_out);
}